// Round 11
// baseline (41127.048 us; speedup 1.0000x reference)
//
#include <hip/hip_runtime.h>
#include <hip/hip_bf16.h>

#define T_STEPS 128
#define DH      512
#define NPATCH  196
#define BATCH   16
#define VOCAB   10000

typedef __attribute__((ext_vector_type(8))) short bf16x8;
typedef __attribute__((ext_vector_type(4))) float f32x4;

__device__ __forceinline__ float sigm(float x) { return 1.0f / (1.0f + __expf(-x)); }
__device__ __forceinline__ float ftanh(float x) {
    float e = __expf(2.0f * x);
    return 1.0f - 2.0f / (e + 1.0f);
}
__device__ __forceinline__ unsigned short f2b(float x) {
    union { float f; unsigned u; } v; v.f = x;
    unsigned r = (v.u + 0x7FFFu + ((v.u >> 16) & 1u)) >> 16;
    return (unsigned short)r;
}
__device__ __forceinline__ float b2f(unsigned short h) {
    union { unsigned u; float f; } v; v.u = ((unsigned)h) << 16;
    return v.f;
}

// ---------------- conversion kernels ----------------
__global__ __launch_bounds__(256)
void cvt_kernel(const float* __restrict__ src, unsigned short* __restrict__ dst, int n)
{
    int i = (blockIdx.x * 256 + threadIdx.x) * 8;
    if (i >= n) return;
    float4 v0 = *(const float4*)(src + i);
    float4 v1 = *(const float4*)(src + i + 4);
    float xs[8] = {v0.x, v0.y, v0.z, v0.w, v1.x, v1.y, v1.z, v1.w};
    bf16x8 o;
#pragma unroll
    for (int j = 0; j < 8; ++j) o[j] = (short)f2b(xs[j]);
    *(bf16x8*)(dst + i) = o;
}

__global__ __launch_bounds__(256)
void cvt_split_kernel(const float* __restrict__ src, unsigned short* __restrict__ hi,
                      unsigned short* __restrict__ lo, int n)
{
    int i = (blockIdx.x * 256 + threadIdx.x) * 8;
    if (i >= n) return;
    float4 v0 = *(const float4*)(src + i);
    float4 v1 = *(const float4*)(src + i + 4);
    float xs[8] = {v0.x, v0.y, v0.z, v0.w, v1.x, v1.y, v1.z, v1.w};
    bf16x8 h_, l_;
#pragma unroll
    for (int j = 0; j < 8; ++j) {
        unsigned short hb = f2b(xs[j]);
        float r = xs[j] - b2f(hb);
        h_[j] = (short)hb;
        l_[j] = (short)f2b(r);
    }
    *(bf16x8*)(hi + i) = h_;
    *(bf16x8*)(lo + i) = l_;
}

// Wcat[j][0..1535] = [Wih[j][0..1023] | Whh[j][0..511]]  (fp32, once)
__global__ __launch_bounds__(256)
void wcat_kernel(const float* __restrict__ Wih, const float* __restrict__ Whh,
                 float* __restrict__ Wcat)
{
    int q = blockIdx.x * 256 + threadIdx.x;     // 2048*384 float4s
    if (q >= 2048 * 384) return;
    int j = q / 384, k4 = q - j * 384;
    float4 v;
    if (k4 < 256) v = ((const float4*)(Wih + (size_t)j * 1024))[k4];
    else          v = ((const float4*)(Whh + (size_t)j * 512))[k4 - 256];
    ((float4*)(Wcat + (size_t)j * 1536))[k4] = v;
}

// ---------------- MFMA GEMM (3-term split; verified round 4) ----------------
__global__ __launch_bounds__(256)
void gemm_mfma(const unsigned short* __restrict__ AH, const unsigned short* __restrict__ AL,
               const unsigned short* __restrict__ WH, const unsigned short* __restrict__ WL,
               const float* __restrict__ bias, float* __restrict__ C,
               unsigned short* __restrict__ CbH, unsigned short* __restrict__ CbL,
               int M, int N, int K)
{
    const int tid = threadIdx.x, wid = tid >> 6, l = tid & 63;
    const int m0 = blockIdx.x * 128 + (wid >> 1) * 64;
    const int n0 = blockIdx.y * 128 + (wid & 1) * 64;
    const int lm = l & 15, lk = (l >> 4) * 8;
    f32x4 acc[4][4];
#pragma unroll
    for (int i = 0; i < 4; ++i)
#pragma unroll
        for (int j = 0; j < 4; ++j) acc[i][j] = (f32x4){0.f, 0.f, 0.f, 0.f};
    const bf16x8 az = {0,0,0,0,0,0,0,0};

    for (int k0 = 0; k0 < K; k0 += 32) {
        bf16x8 aH[4], aL[4];
#pragma unroll
        for (int mi = 0; mi < 4; ++mi) {
            int m = m0 + mi * 16 + lm;
            aH[mi] = (m < M) ? *(const bf16x8*)(AH + (size_t)m * K + k0 + lk) : az;
            aL[mi] = (AL && m < M) ? *(const bf16x8*)(AL + (size_t)m * K + k0 + lk) : az;
        }
#pragma unroll
        for (int ni = 0; ni < 4; ++ni) {
            int n = n0 + ni * 16 + lm;
            bf16x8 bH = az, bL = az;
            if (n < N) {
                bH = *(const bf16x8*)(WH + (size_t)n * K + k0 + lk);
                if (WL) bL = *(const bf16x8*)(WL + (size_t)n * K + k0 + lk);
            }
#pragma unroll
            for (int mi = 0; mi < 4; ++mi) {
                acc[mi][ni] = __builtin_amdgcn_mfma_f32_16x16x32_bf16(aH[mi], bH, acc[mi][ni], 0, 0, 0);
                if (WL) acc[mi][ni] = __builtin_amdgcn_mfma_f32_16x16x32_bf16(aH[mi], bL, acc[mi][ni], 0, 0, 0);
                if (AL) acc[mi][ni] = __builtin_amdgcn_mfma_f32_16x16x32_bf16(aL[mi], bH, acc[mi][ni], 0, 0, 0);
            }
        }
    }
    const int rr = (l >> 4) * 4;
#pragma unroll
    for (int mi = 0; mi < 4; ++mi) {
        int mb = m0 + mi * 16 + rr;
#pragma unroll
        for (int ni = 0; ni < 4; ++ni) {
            int n = n0 + ni * 16 + lm;
            if (n < N) {
                float bs = bias ? bias[n] : 0.f;
#pragma unroll
                for (int r = 0; r < 4; ++r) {
                    int mm = mb + r;
                    if (mm < M) {
                        float v = acc[mi][ni][r] + bs;
                        if (C)   C[(size_t)mm * N + n] = v;
                        if (CbH) {
                            unsigned short hb = f2b(v);
                            CbH[(size_t)mm * N + n] = hb;
                            if (CbL) CbL[(size_t)mm * N + n] = f2b(v - b2f(hb));
                        }
                    }
                }
            }
        }
    }
}

// ---------------- h0 / c0 (fp32) ----------------
__global__ __launch_bounds__(256)
void h0c0_kernel(const float* __restrict__ cls,
                 const float* __restrict__ ihw, const float* __restrict__ ihb,
                 const float* __restrict__ icw, const float* __restrict__ icb,
                 float* __restrict__ c0_g, float* __restrict__ h0_g)
{
    int id = blockIdx.x * 256 + threadIdx.x;   // 0..16383
    int which = id >> 13;
    int b = (id >> 9) & 15;
    int d = id & 511;
    const float* w = (which ? icw : ihw) + d * 768;
    const float* x = cls + b * 768;
    float acc = which ? icb[d] : ihb[d];
    const float4* x4 = (const float4*)x;
    const float4* w4 = (const float4*)w;
#pragma unroll 4
    for (int k = 0; k < 192; ++k) {
        float4 a = x4[k], ww = w4[k];
        acc += a.x * ww.x + a.y * ww.y + a.z * ww.z + a.w * ww.w;
    }
    if (which) c0_g[b * 512 + d] = acc;
    else h0_g[b * 512 + d] = acc;
}

// ---------------- embedding gather (fp32) ----------------
__global__ __launch_bounds__(256)
void gather_kernel(const int* __restrict__ ids, const float* __restrict__ emb,
                   float* __restrict__ x_all)
{
    int q = blockIdx.x * 256 + threadIdx.x;    // 2048 rows * 128 float4
    if (q >= 2048 * 128) return;
    int r = q >> 7, kq = q & 127;
    int tgt = ids[r];
    ((float4*)x_all)[(size_t)r * 128 + kq] = ((const float4*)emb)[(size_t)tgt * 128 + kq];
}

// ---------------- autonomous per-batch recurrence ----------------
// 16 blocks x 1024 threads; block b runs ALL 128 steps for batch b with state in LDS.
// No grid sync, no atomics. Streams: Wcat (12.6MB/step, L3-resident); Wh/keysWk/keys
// L2-resident per XCD. All recurrence math fp32.
__global__ __launch_bounds__(1024, 1)
void batch_recur_kernel(const float* __restrict__ x_all,
                        const float* __restrict__ h0_g, const float* __restrict__ c0_g,
                        const float* __restrict__ keys, const float* __restrict__ keysWk,
                        const float* __restrict__ Wcat, const float* __restrict__ bih,
                        const float* __restrict__ bhh, const float* __restrict__ Wh,
                        const float* __restrict__ lng, const float* __restrict__ lnb,
                        const float* __restrict__ vvec,
                        unsigned short* __restrict__ h_all_b)
{
    __shared__ float zS[1536];        // [x | ctx | hln]
    __shared__ float hS[512], cS[512];
    __shared__ float ewS[512], vvS[512], lngS[512], lnbS[512];
    __shared__ float gbufS[2048], biasS[2048];
    __shared__ float scS[200], alS[200];
    __shared__ float pbS[2][512];
    __shared__ float red[32];

    const int b = blockIdx.x, tid = threadIdx.x;
    const int wv = tid >> 6, ln = tid & 63;

    // one-time loads
    for (int i = tid; i < 2048; i += 1024) biasS[i] = bih[i] + bhh[i];
    if (tid < 512) {
        vvS[tid]  = vvec[tid];
        lngS[tid] = lng[tid];
        lnbS[tid] = lnb[tid];
        hS[tid]   = h0_g[b * 512 + tid];
        cS[tid]   = c0_g[b * 512 + tid];
    }
    __syncthreads();

    for (int t = 0; t < T_STEPS; ++t) {
        // ---- x slice into zS[0..511] ----
        if (tid < 128)
            ((float4*)zS)[tid] = ((const float4*)(x_all + ((size_t)b * T_STEPS + t) * 512))[tid];

        // ---- LN(h) -> zS[1024..1535] (+ h_all row t-1) ----
        if (t > 0) {
            float s1 = 0.f, s2 = 0.f;
            if (tid < 512) { float h = hS[tid]; s1 = h; s2 = h * h; }
#pragma unroll
            for (int m = 1; m < 64; m <<= 1) { s1 += __shfl_xor(s1, m); s2 += __shfl_xor(s2, m); }
            if (tid < 512 && ln == 0) { red[wv] = s1; red[8 + wv] = s2; }
            __syncthreads();
            if (tid == 0) {
                float a1 = 0.f, a2 = 0.f;
#pragma unroll
                for (int i = 0; i < 8; ++i) { a1 += red[i]; a2 += red[8 + i]; }
                float mu = a1 * (1.f / 512.f);
                float var = a2 * (1.f / 512.f) - mu * mu;
                red[16] = mu; red[17] = rsqrtf(var + 1e-5f);
            }
            __syncthreads();
            if (tid < 512) {
                float hv = (hS[tid] - red[16]) * red[17] * lngS[tid] + lnbS[tid];
                zS[1024 + tid] = hv;
                h_all_b[((size_t)b * T_STEPS + (t - 1)) * 512 + tid] = f2b(hv);
            }
        } else {
            if (tid < 512) zS[1024 + tid] = hS[tid];
        }
        __syncthreads();

        // ---- ew[e] = hln . Wh[e,:] : 8 lanes per e, 4 passes ----
        {
            int g8 = tid & 7;
#pragma unroll
            for (int pass = 0; pass < 4; ++pass) {
                int e = pass * 128 + (tid >> 3);
                const float4* wr4 = (const float4*)(Wh + (size_t)e * 512);
                const float4* hh4 = (const float4*)(zS + 1024);
                float s = 0.f;
#pragma unroll
                for (int i = 0; i < 16; ++i) {
                    int k4 = g8 + 8 * i;
                    float4 w4 = wr4[k4], h4 = hh4[k4];
                    s += w4.x * h4.x + w4.y * h4.y + w4.z * h4.z + w4.w * h4.w;
                }
                s += __shfl_xor(s, 1); s += __shfl_xor(s, 2); s += __shfl_xor(s, 4);
                if (g8 == 0) ewS[e] = s;
            }
        }
        __syncthreads();

        // ---- scores[n] = sum_d tanh(ew+kw)*v : 8 lanes per n, 2 passes ----
        {
            int g8 = tid & 7;
#pragma unroll
            for (int pass = 0; pass < 2; ++pass) {
                int n = pass * 128 + (tid >> 3);
                if (n < NPATCH) {
                    const float4* kw4 = (const float4*)(keysWk + ((size_t)(b * NPATCH + n)) * 512);
                    float s = 0.f;
#pragma unroll
                    for (int i = 0; i < 16; ++i) {
                        int k4 = g8 + 8 * i;
                        float4 kk = kw4[k4];
                        int d0 = k4 * 4;
                        s += ftanh(ewS[d0 + 0] + kk.x) * vvS[d0 + 0]
                           + ftanh(ewS[d0 + 1] + kk.y) * vvS[d0 + 1]
                           + ftanh(ewS[d0 + 2] + kk.z) * vvS[d0 + 2]
                           + ftanh(ewS[d0 + 3] + kk.w) * vvS[d0 + 3];
                    }
                    s += __shfl_xor(s, 1); s += __shfl_xor(s, 2); s += __shfl_xor(s, 4);
                    if (g8 == 0) scS[n] = s;
                }
            }
        }
        __syncthreads();

        // ---- softmax over 196 ----
        float sv = (tid < NPATCH) ? scS[tid] : -1e30f;
        {
            float m1 = sv;
#pragma unroll
            for (int m = 1; m < 64; m <<= 1) m1 = fmaxf(m1, __shfl_xor(m1, m));
            if ((tid & 63) == 0 && tid < 256) red[20 + (tid >> 6)] = m1;
        }
        __syncthreads();
        {
            float mx = fmaxf(fmaxf(red[20], red[21]), fmaxf(red[22], red[23]));
            float ev = (tid < NPATCH) ? __expf(sv - mx) : 0.f;
            if (tid < NPATCH) alS[tid] = ev;
            float s2 = ev;
#pragma unroll
            for (int m = 1; m < 64; m <<= 1) s2 += __shfl_xor(s2, m);
            if ((tid & 63) == 0 && tid < 256) red[24 + (tid >> 6)] = s2;
        }
        __syncthreads();

        // ---- ctx[d] -> zS[512..1023] : 2 lanes per d ----
        {
            float inv = 1.f / (red[24] + red[25] + red[26] + red[27]);
            int d = tid & 511, half = tid >> 9;
            const float* kb = keys + (size_t)(b * NPATCH) * 512 + d;
            float acc = 0.f;
            int n0 = half * 98, n1 = n0 + 98;
            for (int n = n0; n < n1; ++n) acc += alS[n] * kb[(size_t)n * 512];
            pbS[half][d] = acc;
            __syncthreads();
            if (tid < 512) zS[512 + tid] = (pbS[0][tid] + pbS[1][tid]) * inv;
        }
        __syncthreads();

        // ---- gates: 2048 dots of 1536 vs streamed fp32 Wcat; 16 lanes/row, 32 passes ----
        {
            int l16 = tid & 15, grp = tid >> 4;   // 64 groups
#pragma unroll 4
            for (int p = 0; p < 32; ++p) {
                int j = grp + (p << 6);
                const float4* wr = (const float4*)(Wcat + (size_t)j * 1536);
                float acc = 0.f;
#pragma unroll
                for (int i = 0; i < 24; ++i) {
                    int k4 = l16 + (i << 4);
                    float4 w4 = wr[k4];
                    float4 z4 = ((const float4*)zS)[k4];
                    acc += w4.x * z4.x + w4.y * z4.y + w4.z * z4.z + w4.w * z4.w;
                }
                acc += __shfl_xor(acc, 1); acc += __shfl_xor(acc, 2);
                acc += __shfl_xor(acc, 4); acc += __shfl_xor(acc, 8);
                if (l16 == 0) gbufS[j] = acc;
            }
        }
        __syncthreads();

        // ---- cell ----
        if (tid < 512) {
            int d = tid;
            float gi = gbufS[d]        + biasS[d];
            float gf = gbufS[512 + d]  + biasS[512 + d];
            float gg = gbufS[1024 + d] + biasS[1024 + d];
            float go = gbufS[1536 + d] + biasS[1536 + d];
            float cn = sigm(gf) * cS[d] + sigm(gi) * ftanh(gg);
            cS[d] = cn;
            hS[d] = sigm(go) * ftanh(cn);
        }
        __syncthreads();
    }

    // ---- final LN -> h_all row 127 ----
    {
        float s1 = 0.f, s2 = 0.f;
        if (tid < 512) { float h = hS[tid]; s1 = h; s2 = h * h; }
#pragma unroll
        for (int m = 1; m < 64; m <<= 1) { s1 += __shfl_xor(s1, m); s2 += __shfl_xor(s2, m); }
        if (tid < 512 && ln == 0) { red[wv] = s1; red[8 + wv] = s2; }
        __syncthreads();
        if (tid == 0) {
            float a1 = 0.f, a2 = 0.f;
#pragma unroll
            for (int i = 0; i < 8; ++i) { a1 += red[i]; a2 += red[8 + i]; }
            float mu = a1 * (1.f / 512.f);
            float var = a2 * (1.f / 512.f) - mu * mu;
            red[16] = mu; red[17] = rsqrtf(var + 1e-5f);
        }
        __syncthreads();
        if (tid < 512) {
            float hv = (hS[tid] - red[16]) * red[17] * lngS[tid] + lnbS[tid];
            h_all_b[((size_t)b * T_STEPS + (T_STEPS - 1)) * 512 + tid] = f2b(hv);
        }
    }
}

extern "C" void kernel_launch(void* const* d_in, const int* in_sizes, int n_in,
                              void* d_out, int out_size, void* d_ws, size_t ws_size,
                              hipStream_t stream)
{
    const float* patches = (const float*)d_in[0];
    const float* cls     = (const float*)d_in[1];
    const int*   tgt     = (const int*)d_in[2];
    const float* kv_w    = (const float*)d_in[3];
    const float* kv_b    = (const float*)d_in[4];
    const float* ih_w    = (const float*)d_in[5];
    const float* ih_b    = (const float*)d_in[6];
    const float* ic_w    = (const float*)d_in[7];
    const float* ic_b    = (const float*)d_in[8];
    const float* emb     = (const float*)d_in[9];
    const float* Wh      = (const float*)d_in[10];
    const float* Wk      = (const float*)d_in[11];
    const float* av      = (const float*)d_in[12];
    const float* Wih     = (const float*)d_in[13];
    const float* Whh     = (const float*)d_in[14];
    const float* bih     = (const float*)d_in[15];
    const float* bhh     = (const float*)d_in[16];
    const float* lng     = (const float*)d_in[17];
    const float* lnb     = (const float*)d_in[18];
    const float* outw    = (const float*)d_in[19];
    const float* outb    = (const float*)d_in[20];
    float* out = (float*)d_out;

    char* wsp = (char*)d_ws;
    auto carve = [&](size_t bytes) -> char* {
        char* p = wsp; wsp += (bytes + 255) & ~(size_t)255; return p;
    };
    float*          keys_f   = (float*)carve((size_t)3136 * 512 * 4);            // 6.4 MB
    float*          keysWk_f = (float*)carve((size_t)3136 * 512 * 4);            // 6.4 MB
    unsigned short* keysH    = (unsigned short*)carve((size_t)3136 * 512 * 2);   // 3.2 MB
    unsigned short* keysL    = (unsigned short*)carve((size_t)3136 * 512 * 2);   // 3.2 MB
    float*          x_all_f  = (float*)carve((size_t)2048 * 512 * 4);            // 4 MB
    unsigned short* h_all_b  = (unsigned short*)carve((size_t)2048 * 512 * 2);   // 2 MB
    float*          Wcat     = (float*)carve((size_t)2048 * 1536 * 4);           // 12.6 MB
    unsigned short* kvwH     = (unsigned short*)carve((size_t)512 * 768 * 2);
    unsigned short* kvwL     = (unsigned short*)carve((size_t)512 * 768 * 2);
    unsigned short* wkH      = (unsigned short*)carve((size_t)512 * 512 * 2);
    unsigned short* wkL      = (unsigned short*)carve((size_t)512 * 512 * 2);
    unsigned short* outw_b   = (unsigned short*)carve((size_t)VOCAB * 512 * 2);  // 10.24 MB
    float* h0_g = (float*)carve((size_t)16 * 512 * 4);
    float* c0_g = (float*)carve((size_t)16 * 512 * 4);
    // patches split aliases outw_b; outw converted after keys GEMM.
    unsigned short* patH = outw_b;
    unsigned short* patL = outw_b + (size_t)3136 * 768;

    auto cvt = [&](const float* s, unsigned short* d, int n) {
        cvt_kernel<<<(n / 8 + 255) / 256, 256, 0, stream>>>(s, d, n);
    };
    auto cvts = [&](const float* s, unsigned short* dh, unsigned short* dl, int n) {
        cvt_split_kernel<<<(n / 8 + 255) / 256, 256, 0, stream>>>(s, dh, dl, n);
    };
    cvts(patches, patH, patL, 3136 * 768);
    cvts(kv_w, kvwH, kvwL, 512 * 768);
    cvts(Wk, wkH, wkL, 512 * 512);

    // keys = patches @ kv_w^T + kv_b : fp32 + split-bf16 outputs
    gemm_mfma<<<dim3(25, 4), 256, 0, stream>>>(patH, patL, kvwH, kvwL, kv_b,
                                               keys_f, keysH, keysL, 3136, 512, 768);
    // patches region free now: convert outw into it
    cvt(outw, outw_b, VOCAB * 512);
    // keysWk = keys @ Wk^T : fp32 out
    gemm_mfma<<<dim3(25, 4), 256, 0, stream>>>(keysH, keysL, wkH, wkL, nullptr,
                                               keysWk_f, nullptr, nullptr, 3136, 512, 512);

    h0c0_kernel<<<64, 256, 0, stream>>>(cls, ih_w, ih_b, ic_w, ic_b, c0_g, h0_g);
    gather_kernel<<<1024, 256, 0, stream>>>(tgt, emb, x_all_f);
    wcat_kernel<<<(2048 * 384 + 255) / 256, 256, 0, stream>>>(Wih, Whh, Wcat);

    // autonomous per-batch recurrence: 16 blocks, no sync, state in LDS
    batch_recur_kernel<<<16, 1024, 0, stream>>>(x_all_f, h0_g, c0_g, keys_f, keysWk_f,
                                                Wcat, bih, bhh, Wh, lng, lnb, av, h_all_b);

    // logits = h_all @ outw^T + out_b  (bf16 MFMA, fp32 out)
    gemm_mfma<<<dim3(16, 79), 256, 0, stream>>>(h_all_b, nullptr, outw_b, nullptr, outb,
                                                out, nullptr, nullptr, 2048, VOCAB, 512);
}

// Round 12
// 8788.471 us; speedup vs baseline: 4.6797x; 4.6797x over previous
//
#include <hip/hip_runtime.h>
#include <hip/hip_bf16.h>

#define T_STEPS 128
#define DH      512
#define NPATCH  196
#define BATCH   16
#define VOCAB   10000

typedef __attribute__((ext_vector_type(8))) short bf16x8;
typedef __attribute__((ext_vector_type(4))) float f32x4;

__device__ __forceinline__ float sigm(float x) { return 1.0f / (1.0f + __expf(-x)); }
__device__ __forceinline__ float ftanh(float x) {
    float e = __expf(2.0f * x);
    return 1.0f - 2.0f / (e + 1.0f);
}
__device__ __forceinline__ unsigned short f2b(float x) {
    union { float f; unsigned u; } v; v.f = x;
    unsigned r = (v.u + 0x7FFFu + ((v.u >> 16) & 1u)) >> 16;
    return (unsigned short)r;
}
__device__ __forceinline__ float b2f(unsigned short h) {
    union { unsigned u; float f; } v; v.u = ((unsigned)h) << 16;
    return v.f;
}

// ---------------- conversion kernels ----------------
__global__ __launch_bounds__(256)
void cvt_kernel(const float* __restrict__ src, unsigned short* __restrict__ dst, int n)
{
    int i = (blockIdx.x * 256 + threadIdx.x) * 8;
    if (i >= n) return;
    float4 v0 = *(const float4*)(src + i);
    float4 v1 = *(const float4*)(src + i + 4);
    float xs[8] = {v0.x, v0.y, v0.z, v0.w, v1.x, v1.y, v1.z, v1.w};
    bf16x8 o;
#pragma unroll
    for (int j = 0; j < 8; ++j) o[j] = (short)f2b(xs[j]);
    *(bf16x8*)(dst + i) = o;
}

__global__ __launch_bounds__(256)
void cvt_split_kernel(const float* __restrict__ src, unsigned short* __restrict__ hi,
                      unsigned short* __restrict__ lo, int n)
{
    int i = (blockIdx.x * 256 + threadIdx.x) * 8;
    if (i >= n) return;
    float4 v0 = *(const float4*)(src + i);
    float4 v1 = *(const float4*)(src + i + 4);
    float xs[8] = {v0.x, v0.y, v0.z, v0.w, v1.x, v1.y, v1.z, v1.w};
    bf16x8 h_, l_;
#pragma unroll
    for (int j = 0; j < 8; ++j) {
        unsigned short hb = f2b(xs[j]);
        float r = xs[j] - b2f(hb);
        h_[j] = (short)hb;
        l_[j] = (short)f2b(r);
    }
    *(bf16x8*)(hi + i) = h_;
    *(bf16x8*)(lo + i) = l_;
}

// Wx[j][k] = Wih[j][k], k<512 (x-columns), split
__global__ __launch_bounds__(256)
void cvt_wx_kernel(const float* __restrict__ Wih, unsigned short* __restrict__ WxH,
                   unsigned short* __restrict__ WxL)
{
    int i = (blockIdx.x * 256 + threadIdx.x) * 8;
    if (i >= 2048 * 512) return;
    int j = i >> 9, k = i & 511;
    const float* s = Wih + (size_t)j * 1024 + k;
    float4 v0 = *(const float4*)s, v1 = *(const float4*)(s + 4);
    float xs[8] = {v0.x, v0.y, v0.z, v0.w, v1.x, v1.y, v1.z, v1.w};
    bf16x8 h_, l_;
#pragma unroll
    for (int q = 0; q < 8; ++q) {
        unsigned short hb = f2b(xs[q]);
        h_[q] = (short)hb;
        l_[q] = (short)f2b(xs[q] - b2f(hb));
    }
    *(bf16x8*)(WxH + i) = h_;
    *(bf16x8*)(WxL + i) = l_;
}

// Wg[j][0..1023] = [Wih[j][512..1023] (ctx cols) | Whh[j][0..511]], split
__global__ __launch_bounds__(256)
void cvt_wg_kernel(const float* __restrict__ Wih, const float* __restrict__ Whh,
                   unsigned short* __restrict__ WgH, unsigned short* __restrict__ WgL)
{
    int i = (blockIdx.x * 256 + threadIdx.x) * 8;
    if (i >= 2048 * 1024) return;
    int j = i >> 10, k = i & 1023;
    const float* s = (k < 512) ? (Wih + (size_t)j * 1024 + 512 + k)
                               : (Whh + (size_t)j * 512 + (k - 512));
    float4 v0 = *(const float4*)s, v1 = *(const float4*)(s + 4);
    float xs[8] = {v0.x, v0.y, v0.z, v0.w, v1.x, v1.y, v1.z, v1.w};
    bf16x8 h_, l_;
#pragma unroll
    for (int q = 0; q < 8; ++q) {
        unsigned short hb = f2b(xs[q]);
        h_[q] = (short)hb;
        l_[q] = (short)f2b(xs[q] - b2f(hb));
    }
    *(bf16x8*)(WgH + i) = h_;
    *(bf16x8*)(WgL + i) = l_;
}

// ---------------- MFMA GEMM (3-term split; verified round 4) ----------------
__global__ __launch_bounds__(256)
void gemm_mfma(const unsigned short* __restrict__ AH, const unsigned short* __restrict__ AL,
               const unsigned short* __restrict__ WH, const unsigned short* __restrict__ WL,
               const float* __restrict__ bias, float* __restrict__ C,
               unsigned short* __restrict__ CbH, unsigned short* __restrict__ CbL,
               int M, int N, int K)
{
    const int tid = threadIdx.x, wid = tid >> 6, l = tid & 63;
    const int m0 = blockIdx.x * 128 + (wid >> 1) * 64;
    const int n0 = blockIdx.y * 128 + (wid & 1) * 64;
    const int lm = l & 15, lk = (l >> 4) * 8;
    f32x4 acc[4][4];
#pragma unroll
    for (int i = 0; i < 4; ++i)
#pragma unroll
        for (int j = 0; j < 4; ++j) acc[i][j] = (f32x4){0.f, 0.f, 0.f, 0.f};
    const bf16x8 az = {0,0,0,0,0,0,0,0};

    for (int k0 = 0; k0 < K; k0 += 32) {
        bf16x8 aH[4], aL[4];
#pragma unroll
        for (int mi = 0; mi < 4; ++mi) {
            int m = m0 + mi * 16 + lm;
            aH[mi] = (m < M) ? *(const bf16x8*)(AH + (size_t)m * K + k0 + lk) : az;
            aL[mi] = (AL && m < M) ? *(const bf16x8*)(AL + (size_t)m * K + k0 + lk) : az;
        }
#pragma unroll
        for (int ni = 0; ni < 4; ++ni) {
            int n = n0 + ni * 16 + lm;
            bf16x8 bH = az, bL = az;
            if (n < N) {
                bH = *(const bf16x8*)(WH + (size_t)n * K + k0 + lk);
                if (WL) bL = *(const bf16x8*)(WL + (size_t)n * K + k0 + lk);
            }
#pragma unroll
            for (int mi = 0; mi < 4; ++mi) {
                acc[mi][ni] = __builtin_amdgcn_mfma_f32_16x16x32_bf16(aH[mi], bH, acc[mi][ni], 0, 0, 0);
                if (WL) acc[mi][ni] = __builtin_amdgcn_mfma_f32_16x16x32_bf16(aH[mi], bL, acc[mi][ni], 0, 0, 0);
                if (AL) acc[mi][ni] = __builtin_amdgcn_mfma_f32_16x16x32_bf16(aL[mi], bH, acc[mi][ni], 0, 0, 0);
            }
        }
    }
    const int rr = (l >> 4) * 4;
#pragma unroll
    for (int mi = 0; mi < 4; ++mi) {
        int mb = m0 + mi * 16 + rr;
#pragma unroll
        for (int ni = 0; ni < 4; ++ni) {
            int n = n0 + ni * 16 + lm;
            if (n < N) {
                float bs = bias ? bias[n] : 0.f;
#pragma unroll
                for (int r = 0; r < 4; ++r) {
                    int mm = mb + r;
                    if (mm < M) {
                        float v = acc[mi][ni][r] + bs;
                        if (C)   C[(size_t)mm * N + n] = v;
                        if (CbH) {
                            unsigned short hb = f2b(v);
                            CbH[(size_t)mm * N + n] = hb;
                            if (CbL) CbL[(size_t)mm * N + n] = f2b(v - b2f(hb));
                        }
                    }
                }
            }
        }
    }
}

// ---------------- h0 / c0 ----------------
__global__ __launch_bounds__(256)
void h0c0_kernel(const float* __restrict__ cls,
                 const float* __restrict__ ihw, const float* __restrict__ ihb,
                 const float* __restrict__ icw, const float* __restrict__ icb,
                 float* __restrict__ c_cur, float* __restrict__ h_raw,
                 unsigned short* __restrict__ h_curH, unsigned short* __restrict__ h_curL)
{
    int id = blockIdx.x * 256 + threadIdx.x;
    int which = id >> 13;
    int b = (id >> 9) & 15;
    int d = id & 511;
    const float* w = (which ? icw : ihw) + d * 768;
    const float* x = cls + b * 768;
    float acc = which ? icb[d] : ihb[d];
    const float4* x4 = (const float4*)x;
    const float4* w4 = (const float4*)w;
#pragma unroll 4
    for (int k = 0; k < 192; ++k) {
        float4 a = x4[k], ww = w4[k];
        acc += a.x * ww.x + a.y * ww.y + a.z * ww.z + a.w * ww.w;
    }
    if (which) c_cur[b * 512 + d] = acc;
    else {
        h_raw[b * 512 + d] = acc;
        unsigned short hb = f2b(acc);
        h_curH[b * 512 + d] = hb;
        h_curL[b * 512 + d] = f2b(acc - b2f(hb));
    }
}

// x split gather
__global__ __launch_bounds__(256)
void gather_kernel(const int* __restrict__ ids, const float* __restrict__ emb,
                   unsigned short* __restrict__ xH, unsigned short* __restrict__ xL)
{
    int q = blockIdx.x * 256 + threadIdx.x;
    if (q >= 2048 * 64) return;
    int r = q >> 6, c = (q & 63) * 8;
    int tgt = ids[r];
    const float4* s = (const float4*)(emb + (size_t)tgt * 512 + c);
    float4 v0 = s[0], v1 = s[1];
    float xs[8] = {v0.x, v0.y, v0.z, v0.w, v1.x, v1.y, v1.z, v1.w};
    bf16x8 oh, ol;
#pragma unroll
    for (int j = 0; j < 8; ++j) {
        unsigned short hb = f2b(xs[j]);
        oh[j] = (short)hb;
        ol[j] = (short)f2b(xs[j] - b2f(hb));
    }
    *(bf16x8*)(xH + (size_t)r * 512 + c) = oh;
    *(bf16x8*)(xL + (size_t)r * 512 + c) = ol;
}

// Per batch: finalize h_{t-1} (LN, split write), ew = h@Wh^T (split W, fp32 h),
// scores (fp32 keysWk), softmax, ctx (fp32 keys).   [round-4 proven; partials width 32]
__global__ __launch_bounds__(1024)
void attn_kernel(int t, const float* __restrict__ partials, const float* __restrict__ h_raw,
                 const float* __restrict__ lng, const float* __restrict__ lnb,
                 unsigned short* __restrict__ h_curH, unsigned short* __restrict__ h_curL,
                 unsigned short* __restrict__ h_all_b,
                 const unsigned short* __restrict__ WhH, const unsigned short* __restrict__ WhL,
                 const float* __restrict__ keysWk_f, const float* __restrict__ keys_f,
                 const float* __restrict__ vvec, float* __restrict__ ctx)
{
    const int b = blockIdx.x, tid = threadIdx.x;
    __shared__ float hn[512], ew[512], vv[512];
    __shared__ float pbuf[4][512];
    __shared__ float sc[200], al[200], mred[4];

    if (t > 0) {
        if (tid < 32) {
            const float* pp = partials + ((size_t)b * 32 + tid) * 2;
            float v1 = pp[0], v2 = pp[1];
#pragma unroll
            for (int m = 1; m < 32; m <<= 1) { v1 += __shfl_xor(v1, m); v2 += __shfl_xor(v2, m); }
            if (tid == 0) {
                float mu = v1 * (1.f / 512.f);
                float var = v2 * (1.f / 512.f) - mu * mu;
                mred[0] = mu; mred[1] = rsqrtf(var + 1e-5f);
            }
        }
        __syncthreads();
        if (tid < 512) {
            float hv = (h_raw[b * 512 + tid] - mred[0]) * mred[1] * lng[tid] + lnb[tid];
            hn[tid] = hv;
            unsigned short hb_ = f2b(hv);
            h_curH[b * 512 + tid] = hb_;
            h_curL[b * 512 + tid] = f2b(hv - b2f(hb_));
            h_all_b[((size_t)b * T_STEPS + (t - 1)) * 512 + tid] = hb_;
        }
    } else {
        if (tid < 512) hn[tid] = h_raw[b * 512 + tid];
    }
    if (tid < 512) vv[tid] = vvec[tid];
    __syncthreads();

    // ew[e] = hn . (WhH[e,:]+WhL[e,:])  — 2 threads/e
    {
        int e = tid & 511, half = tid >> 9;
        const bf16x8* wh = (const bf16x8*)(WhH + (size_t)e * 512) + half * 32;
        const bf16x8* wl = (const bf16x8*)(WhL + (size_t)e * 512) + half * 32;
        const float* hh = hn + half * 256;
        float s = 0.f;
        for (int q = 0; q < 32; ++q) {
            bf16x8 a = wh[q], c = wl[q];
#pragma unroll
            for (int j = 0; j < 8; ++j)
                s += (b2f((unsigned short)a[j]) + b2f((unsigned short)c[j])) * hh[q * 8 + j];
        }
        pbuf[half][e] = s;
    }
    __syncthreads();
    if (tid < 512) ew[tid] = pbuf[0][tid] + pbuf[1][tid];
    __syncthreads();

    // scores[n] = sum_d tanh(ew[d]+keysWk[b,n,d]) * v[d]; one wave per n
    {
        int wid = tid >> 6, lane = tid & 63;
        for (int n = wid; n < NPATCH; n += 16) {
            const float* kwp = keysWk_f + ((size_t)(b * NPATCH + n)) * 512 + lane * 8;
            float4 k0 = ((const float4*)kwp)[0], k1 = ((const float4*)kwp)[1];
            float kv[8] = {k0.x, k0.y, k0.z, k0.w, k1.x, k1.y, k1.z, k1.w};
            float s = 0.f;
#pragma unroll
            for (int j = 0; j < 8; ++j) {
                int d = lane * 8 + j;
                s += ftanh(ew[d] + kv[j]) * vv[d];
            }
#pragma unroll
            for (int m = 32; m; m >>= 1) s += __shfl_xor(s, m, 64);
            if (lane == 0) sc[n] = s;
        }
    }
    __syncthreads();
    if (tid < 64) {
        float m = -1e30f;
        for (int i = tid; i < NPATCH; i += 64) m = fmaxf(m, sc[i]);
#pragma unroll
        for (int k = 32; k; k >>= 1) m = fmaxf(m, __shfl_xor(m, k, 64));
        if (tid == 0) mred[2] = m;
    }
    __syncthreads();
    if (tid < NPATCH) al[tid] = __expf(sc[tid] - mred[2]);
    __syncthreads();
    if (tid < 64) {
        float s = 0.f;
        for (int i = tid; i < NPATCH; i += 64) s += al[i];
#pragma unroll
        for (int k = 32; k; k >>= 1) s += __shfl_xor(s, k, 64);
        if (tid == 0) mred[3] = 1.f / s;
    }
    __syncthreads();
    {
        int q = tid >> 8, d2 = tid & 255;
        float p0 = 0.f, p1 = 0.f;
        const float* kb = keys_f + (size_t)(b * NPATCH) * 512 + d2 * 2;
        for (int n = q * 49; n < q * 49 + 49; ++n) {
            float2 u = *(const float2*)(kb + (size_t)n * 512);
            p0 += al[n] * u.x;
            p1 += al[n] * u.y;
        }
        pbuf[q][d2 * 2] = p0; pbuf[q][d2 * 2 + 1] = p1;
    }
    __syncthreads();
    if (tid < 512)
        ctx[b * 512 + tid] = (pbuf[0][tid] + pbuf[1][tid] + pbuf[2][tid] + pbuf[3][tid]) * mred[3];
}

// grid (32 d-blocks x 2 b-groups), 256 thr (4 waves = 4 gate types), 8 batches/block,
// 16 d's per gate per block. gates = XG + [ctx|hln]@(WgH+WgL)^T + bias (3-term MFMA).
__global__ __launch_bounds__(256)
void gates_kernel(int t, const float* __restrict__ XG, const float* __restrict__ ctx,
                  const unsigned short* __restrict__ hH, const unsigned short* __restrict__ hL,
                  const unsigned short* __restrict__ WgH, const unsigned short* __restrict__ WgL,
                  const float* __restrict__ bih, const float* __restrict__ bhh,
                  float* __restrict__ c_cur, float* __restrict__ h_raw,
                  float* __restrict__ partials)
{
    __shared__ unsigned short zsH[8][1040], zsL[8][1040];
    __shared__ float gl[8][68];
    __shared__ float bias_l[64];
    const int tid = threadIdx.x, blk = blockIdx.x, bgrp = blockIdx.y;
    {
        int bb = tid >> 5, seg = tid & 31;
        int b = bgrp * 8 + bb;
        if (seg < 16) {          // ctx chunk: 32 fp32, split on the fly
            int c = seg * 32;
            const float4* cs = (const float4*)(ctx + b * 512 + c);
#pragma unroll
            for (int q = 0; q < 8; ++q) {
                float4 v = cs[q];
                float xs[4] = {v.x, v.y, v.z, v.w};
#pragma unroll
                for (int i2 = 0; i2 < 4; ++i2) {
                    unsigned short hb = f2b(xs[i2]);
                    zsH[bb][c + q * 4 + i2] = hb;
                    zsL[bb][c + q * 4 + i2] = f2b(xs[i2] - b2f(hb));
                }
            }
        } else {                 // hln chunk: 32 bf16 pairs
            int c = (seg - 16) * 32;
            const bf16x8* sH = (const bf16x8*)(hH + b * 512 + c);
            const bf16x8* sL = (const bf16x8*)(hL + b * 512 + c);
            bf16x8* dH = (bf16x8*)&zsH[bb][512 + c];
            bf16x8* dL = (bf16x8*)&zsL[bb][512 + c];
#pragma unroll
            for (int q = 0; q < 4; ++q) { dH[q] = sH[q]; dL[q] = sL[q]; }
        }
    }
    if (tid < 64) {
        int j = (tid >> 4) * 512 + blk * 16 + (tid & 15);
        bias_l[tid] = bih[j] + bhh[j];
    }
    __syncthreads();

    const int wid = tid >> 6, l = tid & 63, lb = l & 15, lk = (l >> 4) * 8, bbl = lb & 7;
    f32x4 acc0 = {0.f, 0.f, 0.f, 0.f};
    const int j = wid * 512 + blk * 16 + lb;
    const unsigned short* WH_ = WgH + (size_t)j * 1024;
    const unsigned short* WL_ = WgL + (size_t)j * 1024;
    for (int k0 = 0; k0 < 1024; k0 += 32) {
        bf16x8 aH = *(const bf16x8*)&zsH[bbl][k0 + lk];
        bf16x8 aL = *(const bf16x8*)&zsL[bbl][k0 + lk];
        bf16x8 bH = *(const bf16x8*)(WH_ + k0 + lk);
        bf16x8 bL = *(const bf16x8*)(WL_ + k0 + lk);
        acc0 = __builtin_amdgcn_mfma_f32_16x16x32_bf16(aH, bH, acc0, 0, 0, 0);
        acc0 = __builtin_amdgcn_mfma_f32_16x16x32_bf16(aH, bL, acc0, 0, 0, 0);
        acc0 = __builtin_amdgcn_mfma_f32_16x16x32_bf16(aL, bH, acc0, 0, 0, 0);
    }
    {
        int brow = (l >> 4) * 4, col = wid * 16 + lb;
#pragma unroll
        for (int r = 0; r < 4; ++r)
            if (brow + r < 8) gl[brow + r][col] = acc0[r];
    }
    __syncthreads();
    if (tid < 128) {
        int bb = tid >> 4, dl = tid & 15;
        int b = bgrp * 8 + bb, dg = blk * 16 + dl;
        const float* xg = XG + ((size_t)b * T_STEPS + t) * 2048;
        float gi = gl[bb][dl]      + bias_l[dl]      + xg[dg];
        float gf = gl[bb][16 + dl] + bias_l[16 + dl] + xg[512 + dg];
        float gg = gl[bb][32 + dl] + bias_l[32 + dl] + xg[1024 + dg];
        float go = gl[bb][48 + dl] + bias_l[48 + dl] + xg[1536 + dg];
        float c = c_cur[b * 512 + dg];
        float cn = sigm(gf) * c + sigm(gi) * ftanh(gg);
        c_cur[b * 512 + dg] = cn;
        float hr = sigm(go) * ftanh(cn);
        h_raw[b * 512 + dg] = hr;
        float s1 = hr, s2 = hr * hr;
#pragma unroll
        for (int m = 1; m < 16; m <<= 1) { s1 += __shfl_xor(s1, m); s2 += __shfl_xor(s2, m); }
        if (dl == 0) {
            partials[((size_t)b * 32 + blk) * 2 + 0] = s1;
            partials[((size_t)b * 32 + blk) * 2 + 1] = s2;
        }
    }
}

// final step's h (t = 127) -> h_all_b row 127
__global__ __launch_bounds__(512)
void finish_kernel(const float* __restrict__ partials, const float* __restrict__ h_raw,
                   const float* __restrict__ lng, const float* __restrict__ lnb,
                   unsigned short* __restrict__ h_all_b)
{
    int b = blockIdx.x, tid = threadIdx.x;
    __shared__ float mred[2];
    if (tid < 32) {
        const float* pp = partials + ((size_t)b * 32 + tid) * 2;
        float v1 = pp[0], v2 = pp[1];
#pragma unroll
        for (int m = 1; m < 32; m <<= 1) { v1 += __shfl_xor(v1, m); v2 += __shfl_xor(v2, m); }
        if (tid == 0) {
            float mu = v1 * (1.f / 512.f);
            float var = v2 * (1.f / 512.f) - mu * mu;
            mred[0] = mu; mred[1] = rsqrtf(var + 1e-5f);
        }
    }
    __syncthreads();
    float hn = (h_raw[b * 512 + tid] - mred[0]) * mred[1] * lng[tid] + lnb[tid];
    h_all_b[((size_t)b * T_STEPS + (T_STEPS - 1)) * 512 + tid] = f2b(hn);
}

extern "C" void kernel_launch(void* const* d_in, const int* in_sizes, int n_in,
                              void* d_out, int out_size, void* d_ws, size_t ws_size,
                              hipStream_t stream)
{
    const float* patches = (const float*)d_in[0];
    const float* cls     = (const float*)d_in[1];
    const int*   tgt     = (const int*)d_in[2];
    const float* kv_w    = (const float*)d_in[3];
    const float* kv_b    = (const float*)d_in[4];
    const float* ih_w    = (const float*)d_in[5];
    const float* ih_b    = (const float*)d_in[6];
    const float* ic_w    = (const float*)d_in[7];
    const float* ic_b    = (const float*)d_in[8];
    const float* emb     = (const float*)d_in[9];
    const float* Wh      = (const float*)d_in[10];
    const float* Wk      = (const float*)d_in[11];
    const float* av      = (const float*)d_in[12];
    const float* Wih     = (const float*)d_in[13];
    const float* Whh     = (const float*)d_in[14];
    const float* bih     = (const float*)d_in[15];
    const float* bhh     = (const float*)d_in[16];
    const float* lng     = (const float*)d_in[17];
    const float* lnb     = (const float*)d_in[18];
    const float* outw    = (const float*)d_in[19];
    const float* outb    = (const float*)d_in[20];
    float* out = (float*)d_out;

    char* wsp = (char*)d_ws;
    auto carve = [&](size_t bytes) -> char* {
        char* p = wsp; wsp += (bytes + 255) & ~(size_t)255; return p;
    };
    float*          keys_f   = (float*)carve((size_t)3136 * 512 * 4);            // 6.4 MB
    float*          keysWk_f = (float*)carve((size_t)3136 * 512 * 4);            // 6.4 MB
    unsigned short* keysH    = (unsigned short*)carve((size_t)3136 * 512 * 2);   // 3.2 MB
    unsigned short* keysL    = (unsigned short*)carve((size_t)3136 * 512 * 2);   // 3.2 MB
    unsigned short* xH       = (unsigned short*)carve((size_t)2048 * 512 * 2);   // 2 MB
    unsigned short* xL       = (unsigned short*)carve((size_t)2048 * 512 * 2);   // 2 MB
    unsigned short* h_all_b  = (unsigned short*)carve((size_t)2048 * 512 * 2);   // 2 MB
    unsigned short* wgH      = (unsigned short*)carve((size_t)2048 * 1024 * 2);  // 4.2 MB
    unsigned short* wgL      = (unsigned short*)carve((size_t)2048 * 1024 * 2);  // 4.2 MB
    unsigned short* wxH      = (unsigned short*)carve((size_t)2048 * 512 * 2);   // 2.1 MB
    unsigned short* wxL      = (unsigned short*)carve((size_t)2048 * 512 * 2);   // 2.1 MB
    unsigned short* whH      = (unsigned short*)carve((size_t)512 * 512 * 2);
    unsigned short* whL      = (unsigned short*)carve((size_t)512 * 512 * 2);
    unsigned short* kvwH     = (unsigned short*)carve((size_t)512 * 768 * 2);
    unsigned short* kvwL     = (unsigned short*)carve((size_t)512 * 768 * 2);
    unsigned short* wkH      = (unsigned short*)carve((size_t)512 * 512 * 2);
    unsigned short* wkL      = (unsigned short*)carve((size_t)512 * 512 * 2);
    char*           R1       = carve((size_t)2048 * 2048 * 4);                   // 16.8 MB multi-use
    float* ctx      = (float*)carve((size_t)16 * 512 * 4);
    float* c_cur    = (float*)carve((size_t)16 * 512 * 4);
    float* h_raw    = (float*)carve((size_t)16 * 512 * 4);
    unsigned short* h_curH = (unsigned short*)carve((size_t)16 * 512 * 2);
    unsigned short* h_curL = (unsigned short*)carve((size_t)16 * 512 * 2);
    float* partials = (float*)carve((size_t)16 * 32 * 2 * 4);
    // R1 timeline: [patches split] -> keys GEMM -> [XG] -> recurrence -> [outw_b] -> logits
    unsigned short* patH   = (unsigned short*)R1;
    unsigned short* patL   = (unsigned short*)R1 + (size_t)3136 * 768;
    float*          XG     = (float*)R1;
    unsigned short* outw_b = (unsigned short*)R1;

    auto cvt = [&](const float* s, unsigned short* d, int n) {
        cvt_kernel<<<(n / 8 + 255) / 256, 256, 0, stream>>>(s, d, n);
    };
    auto cvts = [&](const float* s, unsigned short* dh, unsigned short* dl, int n) {
        cvt_split_kernel<<<(n / 8 + 255) / 256, 256, 0, stream>>>(s, dh, dl, n);
    };
    cvts(patches, patH, patL, 3136 * 768);
    cvts(kv_w, kvwH, kvwL, 512 * 768);
    cvts(Wk, wkH, wkL, 512 * 512);
    cvts(Wh, whH, whL, 512 * 512);
    cvt_wx_kernel<<<512, 256, 0, stream>>>(Wih, wxH, wxL);
    cvt_wg_kernel<<<1024, 256, 0, stream>>>(Wih, Whh, wgH, wgL);
    gather_kernel<<<512, 256, 0, stream>>>(tgt, emb, xH, xL);

    // keys = patches @ kv_w^T + kv_b : fp32 + split-bf16 outputs  (reads R1=patches)
    gemm_mfma<<<dim3(25, 4), 256, 0, stream>>>(patH, patL, kvwH, kvwL, kv_b,
                                               keys_f, keysH, keysL, 3136, 512, 768);
    // keysWk = keys @ Wk^T : fp32 out
    gemm_mfma<<<dim3(25, 4), 256, 0, stream>>>(keysH, keysL, wkH, wkL, nullptr,
                                               keysWk_f, nullptr, nullptr, 3136, 512, 512);
    // XG = x @ Wx^T  (2048 x 2048, K=512, exact split) -> writes R1 (patches dead)
    gemm_mfma<<<dim3(16, 16), 256, 0, stream>>>(xH, xL, wxH, wxL, nullptr,
                                                XG, nullptr, nullptr, 2048, 2048, 512);

    h0c0_kernel<<<64, 256, 0, stream>>>(cls, ih_w, ih_b, ic_w, ic_b, c_cur, h_raw, h_curH, h_curL);

    for (int t = 0; t < T_STEPS; ++t) {
        attn_kernel<<<16, 1024, 0, stream>>>(t, partials, h_raw, lng, lnb, h_curH, h_curL, h_all_b,
                                             whH, whL, keysWk_f, keys_f, av, ctx);
        gates_kernel<<<dim3(32, 2), 256, 0, stream>>>(t, XG, ctx, h_curH, h_curL,
                                                      wgH, wgL, bih, bhh, c_cur, h_raw, partials);
    }
    finish_kernel<<<16, 512, 0, stream>>>(partials, h_raw, lng, lnb, h_all_b);

    // R1 now free (XG dead): convert outw into it, then logits GEMM
    cvt(outw, outw_b, VOCAB * 512);
    gemm_mfma<<<dim3(16, 79), 256, 0, stream>>>(h_all_b, nullptr, outw_b, nullptr, outb,
                                                out, nullptr, nullptr, 2048, VOCAB, 512);
}

// Round 13
// 6467.905 us; speedup vs baseline: 6.3586x; 1.3588x over previous
//
#include <hip/hip_runtime.h>
#include <hip/hip_bf16.h>

#define T_STEPS 128
#define DH      512
#define NPATCH  196
#define BATCH   16
#define VOCAB   10000
#define NB5     64

typedef __attribute__((ext_vector_type(8))) short bf16x8;
typedef __attribute__((ext_vector_type(4))) float f32x4;

__device__ __forceinline__ float sigm(float x) { return 1.0f / (1.0f + __expf(-x)); }
__device__ __forceinline__ float ftanh(float x) {
    float e = __expf(2.0f * x);
    return 1.0f - 2.0f / (e + 1.0f);
}
__device__ __forceinline__ unsigned short f2b(float x) {
    union { float f; unsigned u; } v; v.f = x;
    unsigned r = (v.u + 0x7FFFu + ((v.u >> 16) & 1u)) >> 16;
    return (unsigned short)r;
}
__device__ __forceinline__ float b2f(unsigned short h) {
    union { unsigned u; float f; } v; v.u = ((unsigned)h) << 16;
    return v.f;
}
// L2-bypassing coherent access (r10-proven): relaxed agent atomics, no invalidates.
__device__ __forceinline__ float cload(const float* p) {
    return __hip_atomic_load(p, __ATOMIC_RELAXED, __HIP_MEMORY_SCOPE_AGENT);
}
__device__ __forceinline__ void cstore(float* p, float v) {
    __hip_atomic_store(p, v, __ATOMIC_RELAXED, __HIP_MEMORY_SCOPE_AGENT);
}

// ---------------- conversion kernels ----------------
__global__ __launch_bounds__(256)
void cvt_kernel(const float* __restrict__ src, unsigned short* __restrict__ dst, int n)
{
    int i = (blockIdx.x * 256 + threadIdx.x) * 8;
    if (i >= n) return;
    float4 v0 = *(const float4*)(src + i);
    float4 v1 = *(const float4*)(src + i + 4);
    float xs[8] = {v0.x, v0.y, v0.z, v0.w, v1.x, v1.y, v1.z, v1.w};
    bf16x8 o;
#pragma unroll
    for (int j = 0; j < 8; ++j) o[j] = (short)f2b(xs[j]);
    *(bf16x8*)(dst + i) = o;
}

__global__ __launch_bounds__(256)
void cvt_split_kernel(const float* __restrict__ src, unsigned short* __restrict__ hi,
                      unsigned short* __restrict__ lo, int n)
{
    int i = (blockIdx.x * 256 + threadIdx.x) * 8;
    if (i >= n) return;
    float4 v0 = *(const float4*)(src + i);
    float4 v1 = *(const float4*)(src + i + 4);
    float xs[8] = {v0.x, v0.y, v0.z, v0.w, v1.x, v1.y, v1.z, v1.w};
    bf16x8 h_, l_;
#pragma unroll
    for (int j = 0; j < 8; ++j) {
        unsigned short hb = f2b(xs[j]);
        float r = xs[j] - b2f(hb);
        h_[j] = (short)hb;
        l_[j] = (short)f2b(r);
    }
    *(bf16x8*)(hi + i) = h_;
    *(bf16x8*)(lo + i) = l_;
}

// Wx[j][k] = Wih[j][k], k<512 (x-columns), split
__global__ __launch_bounds__(256)
void cvt_wx_kernel(const float* __restrict__ Wih, unsigned short* __restrict__ WxH,
                   unsigned short* __restrict__ WxL)
{
    int i = (blockIdx.x * 256 + threadIdx.x) * 8;
    if (i >= 2048 * 512) return;
    int j = i >> 9, k = i & 511;
    const float* s = Wih + (size_t)j * 1024 + k;
    float4 v0 = *(const float4*)s, v1 = *(const float4*)(s + 4);
    float xs[8] = {v0.x, v0.y, v0.z, v0.w, v1.x, v1.y, v1.z, v1.w};
    bf16x8 h_, l_;
#pragma unroll
    for (int q = 0; q < 8; ++q) {
        unsigned short hb = f2b(xs[q]);
        h_[q] = (short)hb;
        l_[q] = (short)f2b(xs[q] - b2f(hb));
    }
    *(bf16x8*)(WxH + i) = h_;
    *(bf16x8*)(WxL + i) = l_;
}

// ---------------- MFMA GEMM (3-term split; verified round 4) ----------------
__global__ __launch_bounds__(256)
void gemm_mfma(const unsigned short* __restrict__ AH, const unsigned short* __restrict__ AL,
               const unsigned short* __restrict__ WH, const unsigned short* __restrict__ WL,
               const float* __restrict__ bias, float* __restrict__ C,
               unsigned short* __restrict__ CbH, unsigned short* __restrict__ CbL,
               int M, int N, int K)
{
    const int tid = threadIdx.x, wid = tid >> 6, l = tid & 63;
    const int m0 = blockIdx.x * 128 + (wid >> 1) * 64;
    const int n0 = blockIdx.y * 128 + (wid & 1) * 64;
    const int lm = l & 15, lk = (l >> 4) * 8;
    f32x4 acc[4][4];
#pragma unroll
    for (int i = 0; i < 4; ++i)
#pragma unroll
        for (int j = 0; j < 4; ++j) acc[i][j] = (f32x4){0.f, 0.f, 0.f, 0.f};
    const bf16x8 az = {0,0,0,0,0,0,0,0};

    for (int k0 = 0; k0 < K; k0 += 32) {
        bf16x8 aH[4], aL[4];
#pragma unroll
        for (int mi = 0; mi < 4; ++mi) {
            int m = m0 + mi * 16 + lm;
            aH[mi] = (m < M) ? *(const bf16x8*)(AH + (size_t)m * K + k0 + lk) : az;
            aL[mi] = (AL && m < M) ? *(const bf16x8*)(AL + (size_t)m * K + k0 + lk) : az;
        }
#pragma unroll
        for (int ni = 0; ni < 4; ++ni) {
            int n = n0 + ni * 16 + lm;
            bf16x8 bH = az, bL = az;
            if (n < N) {
                bH = *(const bf16x8*)(WH + (size_t)n * K + k0 + lk);
                if (WL) bL = *(const bf16x8*)(WL + (size_t)n * K + k0 + lk);
            }
#pragma unroll
            for (int mi = 0; mi < 4; ++mi) {
                acc[mi][ni] = __builtin_amdgcn_mfma_f32_16x16x32_bf16(aH[mi], bH, acc[mi][ni], 0, 0, 0);
                if (WL) acc[mi][ni] = __builtin_amdgcn_mfma_f32_16x16x32_bf16(aH[mi], bL, acc[mi][ni], 0, 0, 0);
                if (AL) acc[mi][ni] = __builtin_amdgcn_mfma_f32_16x16x32_bf16(aL[mi], bH, acc[mi][ni], 0, 0, 0);
            }
        }
    }
    const int rr = (l >> 4) * 4;
#pragma unroll
    for (int mi = 0; mi < 4; ++mi) {
        int mb = m0 + mi * 16 + rr;
#pragma unroll
        for (int ni = 0; ni < 4; ++ni) {
            int n = n0 + ni * 16 + lm;
            if (n < N) {
                float bs = bias ? bias[n] : 0.f;
#pragma unroll
                for (int r = 0; r < 4; ++r) {
                    int mm = mb + r;
                    if (mm < M) {
                        float v = acc[mi][ni][r] + bs;
                        if (C)   C[(size_t)mm * N + n] = v;
                        if (CbH) {
                            unsigned short hb = f2b(v);
                            CbH[(size_t)mm * N + n] = hb;
                            if (CbL) CbL[(size_t)mm * N + n] = f2b(v - b2f(hb));
                        }
                    }
                }
            }
        }
    }
}

// ---------------- h0 / c0 (fp32) ----------------
__global__ __launch_bounds__(256)
void h0c0_kernel(const float* __restrict__ cls,
                 const float* __restrict__ ihw, const float* __restrict__ ihb,
                 const float* __restrict__ icw, const float* __restrict__ icb,
                 float* __restrict__ c_g, float* __restrict__ h_raw0)
{
    int id = blockIdx.x * 256 + threadIdx.x;
    int which = id >> 13;
    int b = (id >> 9) & 15;
    int d = id & 511;
    const float* w = (which ? icw : ihw) + d * 768;
    const float* x = cls + b * 768;
    float acc = which ? icb[d] : ihb[d];
    const float4* x4 = (const float4*)x;
    const float4* w4 = (const float4*)w;
#pragma unroll 4
    for (int k = 0; k < 192; ++k) {
        float4 a = x4[k], ww = w4[k];
        acc += a.x * ww.x + a.y * ww.y + a.z * ww.z + a.w * ww.w;
    }
    if (which) c_g[b * 512 + d] = acc;
    else h_raw0[b * 512 + d] = acc;
}

// x split gather (feeds XG GEMM)
__global__ __launch_bounds__(256)
void gather_kernel(const int* __restrict__ ids, const float* __restrict__ emb,
                   unsigned short* __restrict__ xH, unsigned short* __restrict__ xL)
{
    int q = blockIdx.x * 256 + threadIdx.x;
    if (q >= 2048 * 64) return;
    int r = q >> 6, c = (q & 63) * 8;
    int tgt = ids[r];
    const float4* s = (const float4*)(emb + (size_t)tgt * 512 + c);
    float4 v0 = s[0], v1 = s[1];
    float xs[8] = {v0.x, v0.y, v0.z, v0.w, v1.x, v1.y, v1.z, v1.w};
    bf16x8 oh, ol;
#pragma unroll
    for (int j = 0; j < 8; ++j) {
        unsigned short hb = f2b(xs[j]);
        oh[j] = (short)hb;
        ol[j] = (short)f2b(xs[j] - b2f(hb));
    }
    *(bf16x8*)(xH + (size_t)r * 512 + c) = oh;
    *(bf16x8*)(xL + (size_t)r * 512 + c) = ol;
}

// ---------------- hierarchical grid barrier — ALL RELAXED (r10-proven) ----------------
__device__ __forceinline__ void gbar(int* bar, int gen)
{
    __syncthreads();
    if (threadIdx.x == 0) {
        const int g = blockIdx.x & 7;
        int a = __hip_atomic_fetch_add(bar + g * 64, 1, __ATOMIC_RELAXED, __HIP_MEMORY_SCOPE_AGENT);
        if (a == gen * 8 - 1) {
            int r = __hip_atomic_fetch_add(bar + 8 * 64, 1, __ATOMIC_RELAXED, __HIP_MEMORY_SCOPE_AGENT);
            if (r == gen * 8 - 1) {
#pragma unroll
                for (int gg = 0; gg < 8; ++gg)
                    __hip_atomic_store(bar + (9 + gg) * 64, gen, __ATOMIC_RELAXED, __HIP_MEMORY_SCOPE_AGENT);
            }
        }
        while (__hip_atomic_load(bar + (9 + g) * 64, __ATOMIC_RELAXED, __HIP_MEMORY_SCOPE_AGENT) < gen)
            __builtin_amdgcn_s_sleep(2);
    }
    __syncthreads();
}

// ---------------- persistent recurrence v5: L2-resident slices ----------------
// 64 blocks x 1024 thr. Block k: batch b_own=k&15, slice q=k>>4 (attn phases);
// d-octet [8k,8k+8) with gate weights K=1024 in REGISTERS (gates phase).
// Per-block cached reads/step: Wh-slice 256KB + keysWk-slice 100KB + keys-slice 100KB
// -> per-XCD < 2MB under any block->XCD mapping. Cross-block state via cload/cstore.
__global__ __launch_bounds__(1024, 2)
void recur5_kernel(float* __restrict__ ctx, float* __restrict__ hln_g,
                   float* __restrict__ h_raw2, float* __restrict__ c_g,
                   float* __restrict__ partials2, float* __restrict__ ew_g,
                   float* __restrict__ sc_g,
                   const float* __restrict__ keys, const float* __restrict__ keysWk,
                   const float* __restrict__ XG,
                   const float* __restrict__ Wih, const float* __restrict__ Whh,
                   const float* __restrict__ bih, const float* __restrict__ bhh,
                   const float* __restrict__ Wh, const float* __restrict__ lng,
                   const float* __restrict__ lnb, const float* __restrict__ vvec,
                   unsigned short* __restrict__ h_all_b, int* __restrict__ bar)
{
    __shared__ float zs[8][1024];     // 32KB: [ctx|hln] for 8 batches/pass
    __shared__ float hv[512], ewS[512], vvS[512];
    __shared__ float alS[200];
    __shared__ float pb[8][128];
    __shared__ float gbuf[16][32];
    __shared__ float bias_l[32], red[32];

    const int k = blockIdx.x, tid = threadIdx.x;
    const int b_own = k & 15, q = k >> 4;
    const int rrow = tid >> 5, ks = tid & 31;

    // one-time: gate weights K=1024 ([Wih ctx-cols | Whh]) into registers
    float wreg[32];
    {
        int g = rrow >> 3, dd = rrow & 7;
        int j = g * 512 + 8 * k + dd;
        const float* wc = Wih + (size_t)j * 1024 + 512;
        const float* wh2 = Whh + (size_t)j * 512;
#pragma unroll
        for (int i = 0; i < 32; ++i) {
            int kk = ks + 32 * i;
            wreg[i] = (kk < 512) ? wc[kk] : wh2[kk - 512];
        }
        if (tid < 32) {
            int g2 = tid >> 3, dd2 = tid & 7, j2 = g2 * 512 + 8 * k + dd2;
            bias_l[tid] = bih[j2] + bhh[j2];
        }
        if (tid < 512) vvS[tid] = vvec[tid];
    }
    __syncthreads();

    int gen = 0;
    for (int t = 0; t < T_STEPS; ++t) {
        const float* hcur = h_raw2 + (t & 1) * (BATCH * 512);
        float* hnxt = h_raw2 + ((t + 1) & 1) * (BATCH * 512);
        const float* pcur = partials2 + (t & 1) * (BATCH * 64 * 2);
        float* pnxt = partials2 + ((t + 1) & 1) * (BATCH * 64 * 2);

        // ===== P1: LN stats(b_own) -> hv=hln; q==0 publishes hln_g + h_all; ew e-slice =====
        if (t > 0) {
            if (tid < 64) {
                const float* pp = pcur + ((size_t)b_own * 64 + tid) * 2;
                float s1 = cload(pp), s2 = cload(pp + 1);
#pragma unroll
                for (int m = 1; m < 64; m <<= 1) { s1 += __shfl_xor(s1, m); s2 += __shfl_xor(s2, m); }
                if (tid == 0) {
                    float mu = s1 * (1.f / 512.f);
                    float var = s2 * (1.f / 512.f) - mu * mu;
                    red[0] = mu; red[1] = rsqrtf(var + 1e-5f);
                }
            }
        } else if (tid == 0) { red[0] = 0.f; red[1] = 1.f; }
        __syncthreads();
        if (tid < 512) {
            float h = cload(hcur + b_own * 512 + tid);
            float hl = (t > 0) ? (h - red[0]) * red[1] * lng[tid] + lnb[tid] : h;
            hv[tid] = hl;
            if (q == 0) {
                cstore(&hln_g[b_own * 512 + tid], hl);
                if (t > 0) h_all_b[((size_t)b_own * T_STEPS + (t - 1)) * 512 + tid] = f2b(hl);
            }
        }
        __syncthreads();
        {   // ew[e] for e in [q*128, q*128+128): 8 thr/e, Wh rows cached (256KB slice)
            int e = q * 128 + (tid >> 3), g8 = tid & 7;
            const float4* wr4 = (const float4*)(Wh + (size_t)e * 512);
            float s = 0.f;
#pragma unroll
            for (int i = 0; i < 16; ++i) {
                int k4 = g8 + 8 * i;
                float4 w4 = wr4[k4];
                float4 h4 = ((const float4*)hv)[k4];
                s += w4.x * h4.x + w4.y * h4.y + w4.z * h4.z + w4.w * h4.w;
            }
            s += __shfl_xor(s, 1); s += __shfl_xor(s, 2); s += __shfl_xor(s, 4);
            if (g8 == 0) cstore(&ew_g[b_own * 512 + e], s);
        }
        gbar(bar, ++gen);

        // ===== P2: scores n-slice [q*49, q*49+49), keysWk slice cached (100KB) =====
        if (tid < 512) ewS[tid] = cload(&ew_g[b_own * 512 + tid]);
        __syncthreads();
        {
            int nl = tid >> 4, s16 = tid & 15;
            if (nl < 49) {
                int n = q * 49 + nl;
                const float4* kw4 = (const float4*)(keysWk + ((size_t)(b_own * NPATCH + n)) * 512);
                float s = 0.f;
#pragma unroll
                for (int i = 0; i < 8; ++i) {
                    int k4 = s16 + 16 * i;
                    float4 kk = kw4[k4];
                    int d0 = k4 * 4;
                    s += ftanh(ewS[d0 + 0] + kk.x) * vvS[d0 + 0]
                       + ftanh(ewS[d0 + 1] + kk.y) * vvS[d0 + 1]
                       + ftanh(ewS[d0 + 2] + kk.z) * vvS[d0 + 2]
                       + ftanh(ewS[d0 + 3] + kk.w) * vvS[d0 + 3];
                }
                s += __shfl_xor(s, 1); s += __shfl_xor(s, 2);
                s += __shfl_xor(s, 4); s += __shfl_xor(s, 8);
                if (s16 == 0) cstore(&sc_g[b_own * NPATCH + n], s);
            }
        }
        gbar(bar, ++gen);

        // ===== P3: softmax (redundant per block) + ctx d-slice (keys slice cached) =====
        {
            float sv = (tid < NPATCH) ? cload(&sc_g[b_own * NPATCH + tid]) : -1e30f;
            float m1 = sv;
#pragma unroll
            for (int m = 1; m < 64; m <<= 1) m1 = fmaxf(m1, __shfl_xor(m1, m));
            if ((tid & 63) == 0 && tid < 256) red[8 + (tid >> 6)] = m1;
            __syncthreads();
            float mx = fmaxf(fmaxf(red[8], red[9]), fmaxf(red[10], red[11]));
            float ev = (tid < NPATCH) ? __expf(sv - mx) : 0.f;
            if (tid < NPATCH) alS[tid] = ev;
            float s2 = ev;
#pragma unroll
            for (int m = 1; m < 64; m <<= 1) s2 += __shfl_xor(s2, m);
            if ((tid & 63) == 0 && tid < 256) red[12 + (tid >> 6)] = s2;
            __syncthreads();
            float inv = 1.f / (red[12] + red[13] + red[14] + red[15]);
            int d_loc = tid & 127, g8 = tid >> 7;
            const float* kb = keys + (size_t)(b_own * NPATCH) * 512 + q * 128 + d_loc;
            float acc = 0.f;
            for (int n = g8; n < NPATCH; n += 8) acc += alS[n] * kb[(size_t)n * 512];
            pb[g8][d_loc] = acc;
            __syncthreads();
            if (tid < 128) {
                float s = 0.f;
#pragma unroll
                for (int g = 0; g < 8; ++g) s += pb[g][tid];
                cstore(&ctx[b_own * 512 + q * 128 + tid], s * inv);
            }
        }
        gbar(bar, ++gen);

        // ===== P4: gates (reg weights x LDS z) + cell for d-octet =====
#pragma unroll
        for (int p = 0; p < 2; ++p) {
            {   // stage 8 batches' z = [ctx|hln] via cload (4+4 scalars per thread)
                int bb = tid >> 7, d = (tid & 127) * 4;
                int b = p * 8 + bb;
#pragma unroll
                for (int u = 0; u < 4; ++u) {
                    zs[bb][d + u]       = cload(&ctx[b * 512 + d + u]);
                    zs[bb][512 + d + u] = cload(&hln_g[b * 512 + d + u]);
                }
            }
            __syncthreads();
#pragma unroll
            for (int bl = 0; bl < 8; ++bl) {
                float acc = 0.f;
#pragma unroll
                for (int i = 0; i < 32; ++i) acc += wreg[i] * zs[bl][ks + 32 * i];
#pragma unroll
                for (int m = 1; m < 32; m <<= 1) acc += __shfl_xor(acc, m);
                if (ks == 0) gbuf[p * 8 + bl][rrow] = acc;
            }
            __syncthreads();
        }
        if (tid < 128) {
            int bp = tid >> 3, dd = tid & 7, d = 8 * k + dd;
            const float* xg = XG + ((size_t)bp * T_STEPS + t) * 2048;
            float gi = gbuf[bp][dd]      + bias_l[dd]      + xg[d];
            float gf = gbuf[bp][8 + dd]  + bias_l[8 + dd]  + xg[512 + d];
            float gg = gbuf[bp][16 + dd] + bias_l[16 + dd] + xg[1024 + d];
            float go = gbuf[bp][24 + dd] + bias_l[24 + dd] + xg[1536 + d];
            float cn = sigm(gf) * c_g[bp * 512 + d] + sigm(gi) * ftanh(gg);
            c_g[bp * 512 + d] = cn;              // block-private: cached
            float hr = sigm(go) * ftanh(cn);
            cstore(&hnxt[bp * 512 + d], hr);
            float s1 = hr, s2 = hr * hr;
#pragma unroll
            for (int m = 1; m < 8; m <<= 1) { s1 += __shfl_xor(s1, m); s2 += __shfl_xor(s2, m); }
            if (dd == 0) {
                cstore(&pnxt[((size_t)bp * 64 + k) * 2 + 0], s1);
                cstore(&pnxt[((size_t)bp * 64 + k) * 2 + 1], s2);
            }
        }
        gbar(bar, ++gen);
    }

    // tail: final LN -> h_all row 127 (q==0 blocks, b = k)
    if (q == 0) {
        const float* hcur = h_raw2 + (T_STEPS & 1) * (BATCH * 512);
        const float* pcur = partials2 + (T_STEPS & 1) * (BATCH * 64 * 2);
        int b = b_own;
        if (tid < 64) {
            const float* pp = pcur + ((size_t)b * 64 + tid) * 2;
            float s1 = cload(pp), s2 = cload(pp + 1);
#pragma unroll
            for (int m = 1; m < 64; m <<= 1) { s1 += __shfl_xor(s1, m); s2 += __shfl_xor(s2, m); }
            if (tid == 0) {
                float mu = s1 * (1.f / 512.f);
                float var = s2 * (1.f / 512.f) - mu * mu;
                red[0] = mu; red[1] = rsqrtf(var + 1e-5f);
            }
        }
        __syncthreads();
        if (tid < 512) {
            float h = cload(hcur + b * 512 + tid);
            float hv2 = (h - red[0]) * red[1] * lng[tid] + lnb[tid];
            h_all_b[((size_t)b * T_STEPS + (T_STEPS - 1)) * 512 + tid] = f2b(hv2);
        }
    }
}

extern "C" void kernel_launch(void* const* d_in, const int* in_sizes, int n_in,
                              void* d_out, int out_size, void* d_ws, size_t ws_size,
                              hipStream_t stream)
{
    const float* patches = (const float*)d_in[0];
    const float* cls     = (const float*)d_in[1];
    const int*   tgt     = (const int*)d_in[2];
    const float* kv_w    = (const float*)d_in[3];
    const float* kv_b    = (const float*)d_in[4];
    const float* ih_w    = (const float*)d_in[5];
    const float* ih_b    = (const float*)d_in[6];
    const float* ic_w    = (const float*)d_in[7];
    const float* ic_b    = (const float*)d_in[8];
    const float* emb     = (const float*)d_in[9];
    const float* Wh      = (const float*)d_in[10];
    const float* Wk      = (const float*)d_in[11];
    const float* av      = (const float*)d_in[12];
    const float* Wih     = (const float*)d_in[13];
    const float* Whh     = (const float*)d_in[14];
    const float* bih     = (const float*)d_in[15];
    const float* bhh     = (const float*)d_in[16];
    const float* lng     = (const float*)d_in[17];
    const float* lnb     = (const float*)d_in[18];
    const float* outw    = (const float*)d_in[19];
    const float* outb    = (const float*)d_in[20];
    float* out = (float*)d_out;

    char* wsp = (char*)d_ws;
    auto carve = [&](size_t bytes) -> char* {
        char* p = wsp; wsp += (bytes + 255) & ~(size_t)255; return p;
    };
    float*          keys_f   = (float*)carve((size_t)3136 * 512 * 4);            // 6.4 MB
    float*          keysWk_f = (float*)carve((size_t)3136 * 512 * 4);            // 6.4 MB
    unsigned short* keysH    = (unsigned short*)carve((size_t)3136 * 512 * 2);   // 3.2 MB
    unsigned short* keysL    = (unsigned short*)carve((size_t)3136 * 512 * 2);   // 3.2 MB
    unsigned short* xH       = (unsigned short*)carve((size_t)2048 * 512 * 2);   // 2 MB
    unsigned short* xL       = (unsigned short*)carve((size_t)2048 * 512 * 2);   // 2 MB
    unsigned short* h_all_b  = (unsigned short*)carve((size_t)2048 * 512 * 2);   // 2 MB
    unsigned short* wxH      = (unsigned short*)carve((size_t)2048 * 512 * 2);   // 2.1 MB
    unsigned short* wxL      = (unsigned short*)carve((size_t)2048 * 512 * 2);   // 2.1 MB
    unsigned short* kvwH     = (unsigned short*)carve((size_t)512 * 768 * 2);
    unsigned short* kvwL     = (unsigned short*)carve((size_t)512 * 768 * 2);
    unsigned short* wkH      = (unsigned short*)carve((size_t)512 * 512 * 2);
    unsigned short* wkL      = (unsigned short*)carve((size_t)512 * 512 * 2);
    char*           R1       = carve((size_t)2048 * 2048 * 4);                   // 16.8 MB multi-use
    float* ctx      = (float*)carve((size_t)16 * 512 * 4);
    float* hln_g    = (float*)carve((size_t)16 * 512 * 4);
    float* h_raw2   = (float*)carve((size_t)2 * 16 * 512 * 4);
    float* c_g      = (float*)carve((size_t)16 * 512 * 4);
    float* partials2= (float*)carve((size_t)2 * 16 * 64 * 2 * 4);
    float* ew_g     = (float*)carve((size_t)16 * 512 * 4);
    float* sc_g     = (float*)carve((size_t)16 * NPATCH * 4);
    int*   bar      = (int*)carve(8192);
    // R1 timeline: [patches split] -> keys GEMM -> [XG] -> recurrence -> [outw_b] -> logits
    unsigned short* patH   = (unsigned short*)R1;
    unsigned short* patL   = (unsigned short*)R1 + (size_t)3136 * 768;
    float*          XG     = (float*)R1;
    unsigned short* outw_b = (unsigned short*)R1;

    hipMemsetAsync(bar, 0, 8192, stream);

    auto cvt = [&](const float* s, unsigned short* d, int n) {
        cvt_kernel<<<(n / 8 + 255) / 256, 256, 0, stream>>>(s, d, n);
    };
    auto cvts = [&](const float* s, unsigned short* dh, unsigned short* dl, int n) {
        cvt_split_kernel<<<(n / 8 + 255) / 256, 256, 0, stream>>>(s, dh, dl, n);
    };
    cvts(patches, patH, patL, 3136 * 768);
    cvts(kv_w, kvwH, kvwL, 512 * 768);
    cvts(Wk, wkH, wkL, 512 * 512);
    cvt_wx_kernel<<<512, 256, 0, stream>>>(Wih, wxH, wxL);
    gather_kernel<<<512, 256, 0, stream>>>(tgt, emb, xH, xL);

    // keys = patches @ kv_w^T + kv_b : fp32 + split-bf16 outputs (reads R1=patches)
    gemm_mfma<<<dim3(25, 4), 256, 0, stream>>>(patH, patL, kvwH, kvwL, kv_b,
                                               keys_f, keysH, keysL, 3136, 512, 768);
    // keysWk = keys @ Wk^T : fp32 out
    gemm_mfma<<<dim3(25, 4), 256, 0, stream>>>(keysH, keysL, wkH, wkL, nullptr,
                                               keysWk_f, nullptr, nullptr, 3136, 512, 512);
    // XG = x @ Wx^T (2048 x 2048, K=512) -> writes R1 (patches dead)
    gemm_mfma<<<dim3(16, 16), 256, 0, stream>>>(xH, xL, wxH, wxL, nullptr,
                                                XG, nullptr, nullptr, 2048, 2048, 512);

    h0c0_kernel<<<64, 256, 0, stream>>>(cls, ih_w, ih_b, ic_w, ic_b, c_g, h_raw2);

    // persistent recurrence: 64 blocks, 4 relaxed hierarchical barriers/step
    recur5_kernel<<<NB5, 1024, 0, stream>>>(ctx, hln_g, h_raw2, c_g, partials2, ew_g, sc_g,
                                            keys_f, keysWk_f, XG, Wih, Whh, bih, bhh, Wh,
                                            lng, lnb, av, h_all_b, bar);

    // R1 free (XG dead): outw -> bf16, then logits GEMM
    cvt(outw, outw_b, VOCAB * 512);
    gemm_mfma<<<dim3(16, 79), 256, 0, stream>>>(h_all_b, nullptr, outw_b, nullptr, outb,
                                                out, nullptr, nullptr, 2048, VOCAB, 512);
}

// Round 15
// 5003.504 us; speedup vs baseline: 8.2196x; 1.2927x over previous
//
#include <hip/hip_runtime.h>
#include <hip/hip_bf16.h>

#define T_STEPS 128
#define DH      512
#define NPATCH  196
#define BATCH   16
#define VOCAB   10000
#define NB5     64

typedef __attribute__((ext_vector_type(8))) short bf16x8;
typedef __attribute__((ext_vector_type(4))) float f32x4;

__device__ __forceinline__ float sigm(float x) { return 1.0f / (1.0f + __expf(-x)); }
__device__ __forceinline__ float ftanh(float x) {
    float e = __expf(2.0f * x);
    return 1.0f - 2.0f / (e + 1.0f);
}
__device__ __forceinline__ unsigned short f2b(float x) {
    union { float f; unsigned u; } v; v.f = x;
    unsigned r = (v.u + 0x7FFFu + ((v.u >> 16) & 1u)) >> 16;
    return (unsigned short)r;
}
__device__ __forceinline__ float b2f(unsigned short h) {
    union { unsigned u; float f; } v; v.u = ((unsigned)h) << 16;
    return v.f;
}
// L2-bypassing coherent access (r10/r13-proven): relaxed agent atomics -> sc0 sc1 ops.
__device__ __forceinline__ float cload(const float* p) {
    return __hip_atomic_load(p, __ATOMIC_RELAXED, __HIP_MEMORY_SCOPE_AGENT);
}
__device__ __forceinline__ void cstore(float* p, float v) {
    __hip_atomic_store(p, v, __ATOMIC_RELAXED, __HIP_MEMORY_SCOPE_AGENT);
}
// Vector (16B) cache-bypass ops via ext_vector operands (structs like float4 are
// "indirect" aggregates and fail as asm inputs; ext_vector = LLVM vector = VGPR tuple).
// waitcnt lives INSIDE the asm so the output can't be consumed early.
__device__ __forceinline__ f32x4 cload4(const float* p) {
    f32x4 v;
    asm volatile("global_load_dwordx4 %0, %1, off sc0 sc1\n\ts_waitcnt vmcnt(0)"
                 : "=&v"(v) : "v"(p) : "memory");
    return v;
}
__device__ __forceinline__ void cload4x2(const float* p0, const float* p1, f32x4& a, f32x4& b) {
    asm volatile("global_load_dwordx4 %0, %2, off sc0 sc1\n\t"
                 "global_load_dwordx4 %1, %3, off sc0 sc1\n\t"
                 "s_waitcnt vmcnt(0)"
                 : "=&v"(a), "=&v"(b) : "v"(p0), "v"(p1) : "memory");
}
__device__ __forceinline__ void cstore4(float* p, f32x4 v) {
    asm volatile("global_store_dwordx4 %0, %1, off sc0 sc1" :: "v"(p), "v"(v) : "memory");
}

// ---------------- conversion kernels ----------------
__global__ __launch_bounds__(256)
void cvt_kernel(const float* __restrict__ src, unsigned short* __restrict__ dst, int n)
{
    int i = (blockIdx.x * 256 + threadIdx.x) * 8;
    if (i >= n) return;
    float4 v0 = *(const float4*)(src + i);
    float4 v1 = *(const float4*)(src + i + 4);
    float xs[8] = {v0.x, v0.y, v0.z, v0.w, v1.x, v1.y, v1.z, v1.w};
    bf16x8 o;
#pragma unroll
    for (int j = 0; j < 8; ++j) o[j] = (short)f2b(xs[j]);
    *(bf16x8*)(dst + i) = o;
}

__global__ __launch_bounds__(256)
void cvt_split_kernel(const float* __restrict__ src, unsigned short* __restrict__ hi,
                      unsigned short* __restrict__ lo, int n)
{
    int i = (blockIdx.x * 256 + threadIdx.x) * 8;
    if (i >= n) return;
    float4 v0 = *(const float4*)(src + i);
    float4 v1 = *(const float4*)(src + i + 4);
    float xs[8] = {v0.x, v0.y, v0.z, v0.w, v1.x, v1.y, v1.z, v1.w};
    bf16x8 h_, l_;
#pragma unroll
    for (int j = 0; j < 8; ++j) {
        unsigned short hb = f2b(xs[j]);
        float r = xs[j] - b2f(hb);
        h_[j] = (short)hb;
        l_[j] = (short)f2b(r);
    }
    *(bf16x8*)(hi + i) = h_;
    *(bf16x8*)(lo + i) = l_;
}

// Wx[j][k] = Wih[j][k], k<512 (x-columns), split
__global__ __launch_bounds__(256)
void cvt_wx_kernel(const float* __restrict__ Wih, unsigned short* __restrict__ WxH,
                   unsigned short* __restrict__ WxL)
{
    int i = (blockIdx.x * 256 + threadIdx.x) * 8;
    if (i >= 2048 * 512) return;
    int j = i >> 9, k = i & 511;
    const float* s = Wih + (size_t)j * 1024 + k;
    float4 v0 = *(const float4*)s, v1 = *(const float4*)(s + 4);
    float xs[8] = {v0.x, v0.y, v0.z, v0.w, v1.x, v1.y, v1.z, v1.w};
    bf16x8 h_, l_;
#pragma unroll
    for (int q = 0; q < 8; ++q) {
        unsigned short hb = f2b(xs[q]);
        h_[q] = (short)hb;
        l_[q] = (short)f2b(xs[q] - b2f(hb));
    }
    *(bf16x8*)(WxH + i) = h_;
    *(bf16x8*)(WxL + i) = l_;
}

// ---------------- MFMA GEMM (3-term split; verified round 4) ----------------
__global__ __launch_bounds__(256)
void gemm_mfma(const unsigned short* __restrict__ AH, const unsigned short* __restrict__ AL,
               const unsigned short* __restrict__ WH, const unsigned short* __restrict__ WL,
               const float* __restrict__ bias, float* __restrict__ C,
               unsigned short* __restrict__ CbH, unsigned short* __restrict__ CbL,
               int M, int N, int K)
{
    const int tid = threadIdx.x, wid = tid >> 6, l = tid & 63;
    const int m0 = blockIdx.x * 128 + (wid >> 1) * 64;
    const int n0 = blockIdx.y * 128 + (wid & 1) * 64;
    const int lm = l & 15, lk = (l >> 4) * 8;
    f32x4 acc[4][4];
#pragma unroll
    for (int i = 0; i < 4; ++i)
#pragma unroll
        for (int j = 0; j < 4; ++j) acc[i][j] = (f32x4){0.f, 0.f, 0.f, 0.f};
    const bf16x8 az = {0,0,0,0,0,0,0,0};

    for (int k0 = 0; k0 < K; k0 += 32) {
        bf16x8 aH[4], aL[4];
#pragma unroll
        for (int mi = 0; mi < 4; ++mi) {
            int m = m0 + mi * 16 + lm;
            aH[mi] = (m < M) ? *(const bf16x8*)(AH + (size_t)m * K + k0 + lk) : az;
            aL[mi] = (AL && m < M) ? *(const bf16x8*)(AL + (size_t)m * K + k0 + lk) : az;
        }
#pragma unroll
        for (int ni = 0; ni < 4; ++ni) {
            int n = n0 + ni * 16 + lm;
            bf16x8 bH = az, bL = az;
            if (n < N) {
                bH = *(const bf16x8*)(WH + (size_t)n * K + k0 + lk);
                if (WL) bL = *(const bf16x8*)(WL + (size_t)n * K + k0 + lk);
            }
#pragma unroll
            for (int mi = 0; mi < 4; ++mi) {
                acc[mi][ni] = __builtin_amdgcn_mfma_f32_16x16x32_bf16(aH[mi], bH, acc[mi][ni], 0, 0, 0);
                if (WL) acc[mi][ni] = __builtin_amdgcn_mfma_f32_16x16x32_bf16(aH[mi], bL, acc[mi][ni], 0, 0, 0);
                if (AL) acc[mi][ni] = __builtin_amdgcn_mfma_f32_16x16x32_bf16(aL[mi], bH, acc[mi][ni], 0, 0, 0);
            }
        }
    }
    const int rr = (l >> 4) * 4;
#pragma unroll
    for (int mi = 0; mi < 4; ++mi) {
        int mb = m0 + mi * 16 + rr;
#pragma unroll
        for (int ni = 0; ni < 4; ++ni) {
            int n = n0 + ni * 16 + lm;
            if (n < N) {
                float bs = bias ? bias[n] : 0.f;
#pragma unroll
                for (int r = 0; r < 4; ++r) {
                    int mm = mb + r;
                    if (mm < M) {
                        float v = acc[mi][ni][r] + bs;
                        if (C)   C[(size_t)mm * N + n] = v;
                        if (CbH) {
                            unsigned short hb = f2b(v);
                            CbH[(size_t)mm * N + n] = hb;
                            if (CbL) CbL[(size_t)mm * N + n] = f2b(v - b2f(hb));
                        }
                    }
                }
            }
        }
    }
}

// ---------------- h0 / c0 (fp32) ----------------
__global__ __launch_bounds__(256)
void h0c0_kernel(const float* __restrict__ cls,
                 const float* __restrict__ ihw, const float* __restrict__ ihb,
                 const float* __restrict__ icw, const float* __restrict__ icb,
                 float* __restrict__ c_g, float* __restrict__ h_raw0)
{
    int id = blockIdx.x * 256 + threadIdx.x;
    int which = id >> 13;
    int b = (id >> 9) & 15;
    int d = id & 511;
    const float* w = (which ? icw : ihw) + d * 768;
    const float* x = cls + b * 768;
    float acc = which ? icb[d] : ihb[d];
    const float4* x4 = (const float4*)x;
    const float4* w4 = (const float4*)w;
#pragma unroll 4
    for (int k = 0; k < 192; ++k) {
        float4 a = x4[k], ww = w4[k];
        acc += a.x * ww.x + a.y * ww.y + a.z * ww.z + a.w * ww.w;
    }
    if (which) c_g[b * 512 + d] = acc;
    else h_raw0[b * 512 + d] = acc;
}

// x split gather (feeds XG GEMM)
__global__ __launch_bounds__(256)
void gather_kernel(const int* __restrict__ ids, const float* __restrict__ emb,
                   unsigned short* __restrict__ xH, unsigned short* __restrict__ xL)
{
    int q = blockIdx.x * 256 + threadIdx.x;
    if (q >= 2048 * 64) return;
    int r = q >> 6, c = (q & 63) * 8;
    int tgt = ids[r];
    const float4* s = (const float4*)(emb + (size_t)tgt * 512 + c);
    float4 v0 = s[0], v1 = s[1];
    float xs[8] = {v0.x, v0.y, v0.z, v0.w, v1.x, v1.y, v1.z, v1.w};
    bf16x8 oh, ol;
#pragma unroll
    for (int j = 0; j < 8; ++j) {
        unsigned short hb = f2b(xs[j]);
        oh[j] = (short)hb;
        ol[j] = (short)f2b(xs[j] - b2f(hb));
    }
    *(bf16x8*)(xH + (size_t)r * 512 + c) = oh;
    *(bf16x8*)(xL + (size_t)r * 512 + c) = ol;
}

// ---------------- store/poll barriers (no RMW chains; all relaxed) ----------------
// Grid: block stores gen to its own slot; lanes 0..63 poll all 64 slots (divergent
// loop exits when every slot >= gen). Group (4 blocks of same b_own): 4 slots.
// Ordering: __syncthreads() on entry drains vmcnt -> prior bypass stores are at L3
// before the arrival store issues (r10-proven). Slots monotone; 8KB memset/call.
__device__ __forceinline__ void grid_bar(int* slots, int gen)
{
    __syncthreads();
    if (threadIdx.x < 64) {
        if (threadIdx.x == 0)
            __hip_atomic_store(&slots[blockIdx.x], gen, __ATOMIC_RELAXED, __HIP_MEMORY_SCOPE_AGENT);
        while (__hip_atomic_load(&slots[threadIdx.x], __ATOMIC_RELAXED, __HIP_MEMORY_SCOPE_AGENT) < gen)
            __builtin_amdgcn_s_sleep(1);
    }
    __syncthreads();
}
__device__ __forceinline__ void group_bar(int* gslots, int b_own, int q, int gen)
{
    __syncthreads();
    if (threadIdx.x < 4) {
        if (threadIdx.x == 0)
            __hip_atomic_store(&gslots[b_own * 4 + q], gen, __ATOMIC_RELAXED, __HIP_MEMORY_SCOPE_AGENT);
        while (__hip_atomic_load(&gslots[b_own * 4 + threadIdx.x], __ATOMIC_RELAXED, __HIP_MEMORY_SCOPE_AGENT) < gen)
            __builtin_amdgcn_s_sleep(1);
    }
    __syncthreads();
}

// ---------------- persistent recurrence v6: L2-resident slices + cheap sync ----------
// 64 blocks x 1024 thr. Block k: batch b_own=k&15, slice q=k>>4 (attn phases);
// d-octet [8k,8k+8) with gate weights K=1024 in REGISTERS (gates phase).
// Barriers: P1->group P2->group P3->grid P4->grid. Bulk bypass traffic is dwordx4.
__global__ __launch_bounds__(1024, 2)
void recur6_kernel(float* __restrict__ ctx, float* __restrict__ hln_g,
                   float* __restrict__ h_raw2, float* __restrict__ c_g,
                   float* __restrict__ partials2, float* __restrict__ ew_g,
                   float* __restrict__ sc_g,
                   const float* __restrict__ keys, const float* __restrict__ keysWk,
                   const float* __restrict__ XG,
                   const float* __restrict__ Wih, const float* __restrict__ Whh,
                   const float* __restrict__ bih, const float* __restrict__ bhh,
                   const float* __restrict__ Wh, const float* __restrict__ lng,
                   const float* __restrict__ lnb, const float* __restrict__ vvec,
                   unsigned short* __restrict__ h_all_b, int* __restrict__ bar)
{
    __shared__ float zs[8][1024];
    __shared__ float hv[512], ewS[512], vvS[512];
    __shared__ float alS[200];
    __shared__ float pb[8][128];
    __shared__ float gbuf[16][32];
    __shared__ float bias_l[32], red[32];

    const int k = blockIdx.x, tid = threadIdx.x;
    const int b_own = k & 15, q = k >> 4;
    const int rrow = tid >> 5, ks = tid & 31;
    int* gslots = bar + 64;

    // one-time: gate weights K=1024 ([Wih ctx-cols | Whh]) into registers
    float wreg[32];
    {
        int g = rrow >> 3, dd = rrow & 7;
        int j = g * 512 + 8 * k + dd;
        const float* wc = Wih + (size_t)j * 1024 + 512;
        const float* wh2 = Whh + (size_t)j * 512;
#pragma unroll
        for (int i = 0; i < 32; ++i) {
            int kk = ks + 32 * i;
            wreg[i] = (kk < 512) ? wc[kk] : wh2[kk - 512];
        }
        if (tid < 32) {
            int g2 = tid >> 3, dd2 = tid & 7, j2 = g2 * 512 + 8 * k + dd2;
            bias_l[tid] = bih[j2] + bhh[j2];
        }
        if (tid < 512) vvS[tid] = vvec[tid];
    }
    __syncthreads();

    int gen = 0;
    for (int t = 0; t < T_STEPS; ++t) {
        const float* hcur = h_raw2 + (t & 1) * (BATCH * 512);
        float* hnxt = h_raw2 + ((t + 1) & 1) * (BATCH * 512);
        const float* pcur = partials2 + (t & 1) * (BATCH * 64 * 2);
        float* pnxt = partials2 + ((t + 1) & 1) * (BATCH * 64 * 2);

        // ===== P1: LN stats(b_own) -> hv; q==0 publishes hln_g + h_all; ew e-slice =====
        if (t > 0) {
            if (tid < 64) {
                const float* pp = pcur + ((size_t)b_own * 64 + tid) * 2;
                float s1 = cload(pp), s2 = cload(pp + 1);
#pragma unroll
                for (int m = 1; m < 64; m <<= 1) { s1 += __shfl_xor(s1, m); s2 += __shfl_xor(s2, m); }
                if (tid == 0) {
                    float mu = s1 * (1.f / 512.f);
                    float var = s2 * (1.f / 512.f) - mu * mu;
                    red[0] = mu; red[1] = rsqrtf(var + 1e-5f);
                }
            }
        } else if (tid == 0) { red[0] = 0.f; red[1] = 1.f; }
        __syncthreads();
        if (tid < 128) {
            f32x4 h4 = cload4(hcur + b_own * 512 + tid * 4);
            f32x4 o = h4;
            if (t > 0) {
                float mu = red[0], rv = red[1];
                f32x4 g4 = ((const f32x4*)lng)[tid];
                f32x4 bl4 = ((const f32x4*)lnb)[tid];
#pragma unroll
                for (int u = 0; u < 4; ++u) o[u] = (h4[u] - mu) * rv * g4[u] + bl4[u];
            }
            ((f32x4*)hv)[tid] = o;
            if (q == 0) {
                cstore4(&hln_g[b_own * 512 + tid * 4], o);
                if (t > 0) {
                    short4 hb = { (short)f2b(o[0]), (short)f2b(o[1]), (short)f2b(o[2]), (short)f2b(o[3]) };
                    *(short4*)(h_all_b + ((size_t)b_own * T_STEPS + (t - 1)) * 512 + tid * 4) = hb;
                }
            }
        }
        __syncthreads();
        {   // ew[e] for e in [q*128, q*128+128): 8 thr/e, Wh slice cached (256KB)
            int e = q * 128 + (tid >> 3), g8 = tid & 7;
            const float4* wr4 = (const float4*)(Wh + (size_t)e * 512);
            float s = 0.f;
#pragma unroll
            for (int i = 0; i < 16; ++i) {
                int k4 = g8 + 8 * i;
                float4 w4 = wr4[k4];
                float4 h4 = ((const float4*)hv)[k4];
                s += w4.x * h4.x + w4.y * h4.y + w4.z * h4.z + w4.w * h4.w;
            }
            s += __shfl_xor(s, 1); s += __shfl_xor(s, 2); s += __shfl_xor(s, 4);
            if (g8 == 0) cstore(&ew_g[b_own * 512 + e], s);
        }
        group_bar(gslots, b_own, q, ++gen);

        // ===== P2: scores n-slice [q*49, q*49+49), keysWk slice cached (100KB) =====
        if (tid < 128) ((f32x4*)ewS)[tid] = cload4(&ew_g[b_own * 512 + tid * 4]);
        __syncthreads();
        {
            int nl = tid >> 4, s16 = tid & 15;
            if (nl < 49) {
                int n = q * 49 + nl;
                const float4* kw4 = (const float4*)(keysWk + ((size_t)(b_own * NPATCH + n)) * 512);
                float s = 0.f;
#pragma unroll
                for (int i = 0; i < 8; ++i) {
                    int k4 = s16 + 16 * i;
                    float4 kk = kw4[k4];
                    int d0 = k4 * 4;
                    s += ftanh(ewS[d0 + 0] + kk.x) * vvS[d0 + 0]
                       + ftanh(ewS[d0 + 1] + kk.y) * vvS[d0 + 1]
                       + ftanh(ewS[d0 + 2] + kk.z) * vvS[d0 + 2]
                       + ftanh(ewS[d0 + 3] + kk.w) * vvS[d0 + 3];
                }
                s += __shfl_xor(s, 1); s += __shfl_xor(s, 2);
                s += __shfl_xor(s, 4); s += __shfl_xor(s, 8);
                if (s16 == 0) cstore(&sc_g[b_own * NPATCH + n], s);
            }
        }
        group_bar(gslots, b_own, q, ++gen);

        // ===== P3: softmax (redundant per block) + ctx d-slice (keys slice cached) =====
        {
            float sv = (tid < NPATCH) ? cload(&sc_g[b_own * NPATCH + tid]) : -1e30f;
            float m1 = sv;
#pragma unroll
            for (int m = 1; m < 64; m <<= 1) m1 = fmaxf(m1, __shfl_xor(m1, m));
            if ((tid & 63) == 0 && tid < 256) red[8 + (tid >> 6)] = m1;
            __syncthreads();
            float mx = fmaxf(fmaxf(red[8], red[9]), fmaxf(red[10], red[11]));
            float ev = (tid < NPATCH) ? __expf(sv - mx) : 0.f;
            if (tid < NPATCH) alS[tid] = ev;
            float s2 = ev;
#pragma unroll
            for (int m = 1; m < 64; m <<= 1) s2 += __shfl_xor(s2, m);
            if ((tid & 63) == 0 && tid < 256) red[12 + (tid >> 6)] = s2;
            __syncthreads();
            float inv = 1.f / (red[12] + red[13] + red[14] + red[15]);
            int d_loc = tid & 127, g8 = tid >> 7;
            const float* kb = keys + (size_t)(b_own * NPATCH) * 512 + q * 128 + d_loc;
            float acc = 0.f;
            for (int n = g8; n < NPATCH; n += 8) acc += alS[n] * kb[(size_t)n * 512];
            pb[g8][d_loc] = acc;
            __syncthreads();
            if (tid < 128) {
                float s = 0.f;
#pragma unroll
                for (int g = 0; g < 8; ++g) s += pb[g][tid];
                cstore(&ctx[b_own * 512 + q * 128 + tid], s * inv);
            }
        }
        grid_bar(bar, ++gen);

        // ===== P4: gates (reg weights x LDS z) + cell for d-octet =====
#pragma unroll
        for (int p = 0; p < 2; ++p) {
            {   // stage 8 batches' z = [ctx|hln] via paired dwordx4 bypass loads
                int bb = tid >> 7, i4 = (tid & 127) * 4;
                int b = p * 8 + bb;
                f32x4 c4, h4;
                cload4x2(&ctx[b * 512 + i4], &hln_g[b * 512 + i4], c4, h4);
                *(f32x4*)&zs[bb][i4] = c4;
                *(f32x4*)&zs[bb][512 + i4] = h4;
            }
            __syncthreads();
#pragma unroll
            for (int bl = 0; bl < 8; ++bl) {
                float acc = 0.f;
#pragma unroll
                for (int i = 0; i < 32; ++i) acc += wreg[i] * zs[bl][ks + 32 * i];
#pragma unroll
                for (int m = 1; m < 32; m <<= 1) acc += __shfl_xor(acc, m);
                if (ks == 0) gbuf[p * 8 + bl][rrow] = acc;
            }
            __syncthreads();
        }
        if (tid < 128) {
            int bp = tid >> 3, dd = tid & 7, d = 8 * k + dd;
            const float* xg = XG + ((size_t)bp * T_STEPS + t) * 2048;
            float gi = gbuf[bp][dd]      + bias_l[dd]      + xg[d];
            float gf = gbuf[bp][8 + dd]  + bias_l[8 + dd]  + xg[512 + d];
            float gg = gbuf[bp][16 + dd] + bias_l[16 + dd] + xg[1024 + d];
            float go = gbuf[bp][24 + dd] + bias_l[24 + dd] + xg[1536 + d];
            float cn = sigm(gf) * c_g[bp * 512 + d] + sigm(gi) * ftanh(gg);
            c_g[bp * 512 + d] = cn;              // block-private: cached
            float hr = sigm(go) * ftanh(cn);
            cstore(&hnxt[bp * 512 + d], hr);
            float s1 = hr, s2 = hr * hr;
#pragma unroll
            for (int m = 1; m < 8; m <<= 1) { s1 += __shfl_xor(s1, m); s2 += __shfl_xor(s2, m); }
            if (dd == 0) {
                cstore(&pnxt[((size_t)bp * 64 + k) * 2 + 0], s1);
                cstore(&pnxt[((size_t)bp * 64 + k) * 2 + 1], s2);
            }
        }
        grid_bar(bar, ++gen);
    }

    // tail: final LN -> h_all row 127 (q==0 blocks, b = b_own)
    if (q == 0) {
        const float* hcur = h_raw2 + (T_STEPS & 1) * (BATCH * 512);
        const float* pcur = partials2 + (T_STEPS & 1) * (BATCH * 64 * 2);
        int b = b_own;
        if (tid < 64) {
            const float* pp = pcur + ((size_t)b * 64 + tid) * 2;
            float s1 = cload(pp), s2 = cload(pp + 1);
#pragma unroll
            for (int m = 1; m < 64; m <<= 1) { s1 += __shfl_xor(s1, m); s2 += __shfl_xor(s2, m); }
            if (tid == 0) {
                float mu = s1 * (1.f / 512.f);
                float var = s2 * (1.f / 512.f) - mu * mu;
                red[0] = mu; red[1] = rsqrtf(var + 1e-5f);
            }
        }
        __syncthreads();
        if (tid < 128) {
            f32x4 h4 = cload4(hcur + b * 512 + tid * 4);
            float mu = red[0], rv = red[1];
            f32x4 g4 = ((const f32x4*)lng)[tid];
            f32x4 bl4 = ((const f32x4*)lnb)[tid];
            f32x4 o;
#pragma unroll
            for (int u = 0; u < 4; ++u) o[u] = (h4[u] - mu) * rv * g4[u] + bl4[u];
            short4 hb = { (short)f2b(o[0]), (short)f2b(o[1]), (short)f2b(o[2]), (short)f2b(o[3]) };
            *(short4*)(h_all_b + ((size_t)b * T_STEPS + (T_STEPS - 1)) * 512 + tid * 4) = hb;
        }
    }
}

extern "C" void kernel_launch(void* const* d_in, const int* in_sizes, int n_in,
                              void* d_out, int out_size, void* d_ws, size_t ws_size,
                              hipStream_t stream)
{
    const float* patches = (const float*)d_in[0];
    const float* cls     = (const float*)d_in[1];
    const int*   tgt     = (const int*)d_in[2];
    const float* kv_w    = (const float*)d_in[3];
    const float* kv_b    = (const float*)d_in[4];
    const float* ih_w    = (const float*)d_in[5];
    const float* ih_b    = (const float*)d_in[6];
    const float* ic_w    = (const float*)d_in[7];
    const float* ic_b    = (const float*)d_in[8];
    const float* emb     = (const float*)d_in[9];
    const float* Wh      = (const float*)d_in[10];
    const float* Wk      = (const float*)d_in[11];
    const float* av      = (const float*)d_in[12];
    const float* Wih     = (const float*)d_in[13];
    const float* Whh     = (const float*)d_in[14];
    const float* bih     = (const float*)d_in[15];
    const float* bhh     = (const float*)d_in[16];
    const float* lng     = (const float*)d_in[17];
    const float* lnb     = (const float*)d_in[18];
    const float* outw    = (const float*)d_in[19];
    const float* outb    = (const float*)d_in[20];
    float* out = (float*)d_out;

    char* wsp = (char*)d_ws;
    auto carve = [&](size_t bytes) -> char* {
        char* p = wsp; wsp += (bytes + 255) & ~(size_t)255; return p;
    };
    float*          keys_f   = (float*)carve((size_t)3136 * 512 * 4);
    float*          keysWk_f = (float*)carve((size_t)3136 * 512 * 4);
    unsigned short* keysH    = (unsigned short*)carve((size_t)3136 * 512 * 2);
    unsigned short* keysL    = (unsigned short*)carve((size_t)3136 * 512 * 2);
    unsigned short* xH       = (unsigned short*)carve((size_t)2048 * 512 * 2);
    unsigned short* xL       = (unsigned short*)carve((size_t)2048 * 512 * 2);
    unsigned short* h_all_b  = (unsigned short*)carve((size_t)2048 * 512 * 2);
    unsigned short* wxH      = (unsigned short*)carve((size_t)2048 * 512 * 2);
    unsigned short* wxL      = (unsigned short*)carve((size_t)2048 * 512 * 2);
    unsigned short* kvwH     = (unsigned short*)carve((size_t)512 * 768 * 2);
    unsigned short* kvwL     = (unsigned short*)carve((size_t)512 * 768 * 2);
    unsigned short* wkH      = (unsigned short*)carve((size_t)512 * 512 * 2);
    unsigned short* wkL      = (unsigned short*)carve((size_t)512 * 512 * 2);
    char*           R1       = carve((size_t)2048 * 2048 * 4);
    float* ctx      = (float*)carve((size_t)16 * 512 * 4);
    float* hln_g    = (float*)carve((size_t)16 * 512 * 4);
    float* h_raw2   = (float*)carve((size_t)2 * 16 * 512 * 4);
    float* c_g      = (float*)carve((size_t)16 * 512 * 4);
    float* partials2= (float*)carve((size_t)2 * 16 * 64 * 2 * 4);
    float* ew_g     = (float*)carve((size_t)16 * 512 * 4);
    float* sc_g     = (float*)carve((size_t)16 * NPATCH * 4);
    int*   bar      = (int*)carve(8192);
    unsigned short* patH   = (unsigned short*)R1;
    unsigned short* patL   = (unsigned short*)R1 + (size_t)3136 * 768;
    float*          XG     = (float*)R1;
    unsigned short* outw_b = (unsigned short*)R1;

    (void)hipMemsetAsync(bar, 0, 8192, stream);

    auto cvt = [&](const float* s, unsigned short* d, int n) {
        cvt_kernel<<<(n / 8 + 255) / 256, 256, 0, stream>>>(s, d, n);
    };
    auto cvts = [&](const float* s, unsigned short* dh, unsigned short* dl, int n) {
        cvt_split_kernel<<<(n / 8 + 255) / 256, 256, 0, stream>>>(s, dh, dl, n);
    };
    cvts(patches, patH, patL, 3136 * 768);
    cvts(kv_w, kvwH, kvwL, 512 * 768);
    cvts(Wk, wkH, wkL, 512 * 512);
    cvt_wx_kernel<<<512, 256, 0, stream>>>(Wih, wxH, wxL);
    gather_kernel<<<512, 256, 0, stream>>>(tgt, emb, xH, xL);

    // keys = patches @ kv_w^T + kv_b : fp32 + split-bf16 outputs (reads R1=patches)
    gemm_mfma<<<dim3(25, 4), 256, 0, stream>>>(patH, patL, kvwH, kvwL, kv_b,
                                               keys_f, keysH, keysL, 3136, 512, 768);
    // keysWk = keys @ Wk^T : fp32 out
    gemm_mfma<<<dim3(25, 4), 256, 0, stream>>>(keysH, keysL, wkH, wkL, nullptr,
                                               keysWk_f, nullptr, nullptr, 3136, 512, 512);
    // XG = x @ Wx^T (2048 x 2048, K=512) -> writes R1 (patches dead)
    gemm_mfma<<<dim3(16, 16), 256, 0, stream>>>(xH, xL, wxH, wxL, nullptr,
                                                XG, nullptr, nullptr, 2048, 2048, 512);

    h0c0_kernel<<<64, 256, 0, stream>>>(cls, ih_w, ih_b, ic_w, ic_b, c_g, h_raw2);

    // persistent recurrence: 64 blocks, 2 group + 2 grid store/poll barriers per step
    recur6_kernel<<<NB5, 1024, 0, stream>>>(ctx, hln_g, h_raw2, c_g, partials2, ew_g, sc_g,
                                            keys_f, keysWk_f, XG, Wih, Whh, bih, bhh, Wh,
                                            lng, lnb, av, h_all_b, bar);

    // R1 free (XG dead): outw -> bf16, then logits GEMM
    cvt(outw, outw_b, VOCAB * 512);
    gemm_mfma<<<dim3(16, 79), 256, 0, stream>>>(h_all_b, nullptr, outw_b, nullptr, outb,
                                                out, nullptr, nullptr, 2048, VOCAB, 512);
}